// Round 8
// baseline (180.866 us; speedup 1.0000x reference)
//
#include <hip/hip_runtime.h>
#include <math.h>

#define NB 128     // B
#define NN_ 116    // N
#define NK 4       // K
#define NF 72      // F
#define NS 8       // S
#define TOPK 10

#define BK (NB*NK)            // 512
#define BN (NB*NN_)           // 14848
#define NN2 (NN_*NN_)         // 13456
#define KN (NK*NN_)           // 464
#define ROWS (BK*NN_)         // 59392
#define LROW 117              // padded LDS row stride (odd -> conflict-free transpose)

// output section offsets (floats)
#define OFF_UNI 0
#define SZ_UNI (NB*KN*KN)                 // 27557888
#define OFF_NF (OFF_UNI + SZ_UNI)
#define SZ_NF (NB*KN*NF)                  // 4276224
#define OFF_GF (OFF_NF + SZ_NF)
#define SZ_GF (NB*128)
#define OFF_IA (OFF_GF + SZ_GF)
#define SZ_IA (NB*NK*NN_*NN_)             // 6889472
#define OFF_IE (OFF_IA + SZ_IA)
#define SZ_IE (NB*NN_*NK*NK)              // 237568
#define OFF_SP (OFF_IE + SZ_IE)

// scratch inside the unified region (consumed before k_uninf overwrites it)
#define SCR_SC 0                          // sc -> intra in-place (SZ_IA floats)
#define SCR_DENS (SCR_SC + SZ_IA)         // BN
#define SCR_STREN (SCR_DENS + BN)         // BN
#define SCR_AUX (SCR_STREN + BN)          // 2*NB (fallback if ws too small)

__device__ __forceinline__ float sigmoidf_(float x){ return 1.0f/(1.0f+expf(-x)); }
__device__ __forceinline__ float dot4_(float4 a, float4 b){
    return fmaf(a.x,b.x, fmaf(a.y,b.y, fmaf(a.z,b.z, a.w*b.w)));
}
#define CLIP1(x) fminf(1.0f, fmaxf(-1.0f, (x)))

// ============ FAT1: blocks <512 = corr+topk+mask; blocks >=512 = inter ============
__global__ __launch_bounds__(256, 1) void k_front(const float* __restrict__ band,
    const float* __restrict__ attn, const float* __restrict__ thadjA,
    const float* __restrict__ thadjE, const float* __restrict__ fwp,
    const float* __restrict__ eW1, const float* __restrict__ eb1,
    const float* __restrict__ eW2, const float* __restrict__ eb2,
    float* __restrict__ sc_out, float* __restrict__ inter_out,
    float* __restrict__ dens_out, float* __restrict__ stren_out)
{
    __shared__ float sx[NF*120];          // 34.6 KB
    __shared__ float sC[NN_*LROW];        // 54.3 KB
    __shared__ unsigned stop[232*10];     // 9.3 KB
    __shared__ unsigned skm[NN_*4];
    __shared__ float smu[120], srs[120];
    __shared__ float sW1[128], sb1[32], sW2[128], sb2[4];
    __shared__ float sMat[256*4];
    int t = threadIdx.x;
    if (blockIdx.x < 512){
        // -------- corr --------
        int bk = blockIdx.x;
        int b = bk >> 2, k = bk & 3;
        const float* xin = band + ((size_t)b*NN_*NK + k)*NF;
        for (int e = t; e < NN_*NF; e += 256){
            int n = e / NF, f = e - n*NF;
            sx[f*120 + n] = xin[(size_t)n*NK*NF + f];
        }
        for (int e = t; e < NF*4; e += 256)
            sx[(e>>2)*120 + NN_ + (e&3)] = 0.0f;
        __syncthreads();
        if (t < NN_){
            float s = 0.f, ss = 0.f;
            for (int f = 0; f < NF; ++f){ float v = sx[f*120+t]; s += v; ss += v*v; }
            float mu = s * (1.0f/NF);
            float sd = sqrtf(fmaxf(ss - s*mu, 1e-8f));
            smu[t] = mu; srs[t] = 1.0f/sd;
        }
        __syncthreads();
        for (int e = t; e < NF*NN_; e += 256){
            int f = e / NN_, n = e - f*NN_;
            sx[f*120+n] = (sx[f*120+n] - smu[n]) * srs[n];
        }
        __syncthreads();
        if (t < 225){
            int ti = t / 15, tj = t - ti*15;
            int i0 = ti*8, j0 = tj*8;
            float acc[8][8] = {};
            for (int f = 0; f < NF; ++f){
                const float4 a0 = *(const float4*)&sx[f*120 + i0];
                const float4 a1 = *(const float4*)&sx[f*120 + i0 + 4];
                const float4 c0 = *(const float4*)&sx[f*120 + j0];
                const float4 c1 = *(const float4*)&sx[f*120 + j0 + 4];
                float av[8] = {a0.x,a0.y,a0.z,a0.w,a1.x,a1.y,a1.z,a1.w};
                float cv[8] = {c0.x,c0.y,c0.z,c0.w,c1.x,c1.y,c1.z,c1.w};
                #pragma unroll
                for (int r = 0; r < 8; ++r)
                    #pragma unroll
                    for (int c = 0; c < 8; ++c)
                        acc[r][c] = fmaf(av[r], cv[c], acc[r][c]);
            }
            #pragma unroll
            for (int r = 0; r < 8; ++r){
                int i = i0 + r;
                if (i < NN_){
                    #pragma unroll
                    for (int c = 0; c < 8; ++c){
                        int j = j0 + c;
                        if (j < NN_) sC[i*LROW + j] = CLIP1(acc[r][c]);
                    }
                }
            }
        }
        __syncthreads();
        // -------- top-10, 2 threads/row, packed keys --------
        if (t < 232){
            int r = t >> 1, h = t & 1;
            const float* row = &sC[r*LROW + h*58];
            int jbase = h*58;
            unsigned tv[TOPK];
            #pragma unroll
            for (int p = 0; p < TOPK; ++p) tv[p] = 0u;
            for (int jj = 0; jj < 58; ++jj){
                float c = fabsf(row[jj]);
                unsigned u = (__float_as_uint(c) & 0xFFFFFF80u) | (unsigned)(127 - (jbase + jj));
                #pragma unroll
                for (int p = 0; p < TOPK; ++p){
                    unsigned old = tv[p];
                    bool gt = u > old;
                    tv[p] = gt ? u : old;
                    u = gt ? old : u;
                }
            }
            #pragma unroll
            for (int p = 0; p < TOPK; ++p) stop[t*10 + p] = tv[p];
        }
        __syncthreads();
        if (t < NN_){
            const unsigned* A = &stop[(2*t)*10];
            const unsigned* Bp = &stop[(2*t+1)*10];
            int pa = 0, pb = 0;
            unsigned m0=0,m1=0,m2=0,m3=0;
            #pragma unroll
            for (int p = 0; p < TOPK; ++p){
                unsigned ua = A[pa], ub = Bp[pb];
                unsigned u;
                if (ua > ub){ u = ua; ++pa; } else { u = ub; ++pb; }
                int j = 127 - (int)(u & 127u);
                unsigned bit = 1u << (j & 31);
                int w = j >> 5;
                if (w == 0) m0 |= bit; else if (w == 1) m1 |= bit; else if (w == 2) m2 |= bit; else m3 |= bit;
            }
            skm[t*4+0]=m0; skm[t*4+1]=m1; skm[t*4+2]=m2; skm[t*4+3]=m3;
        }
        __syncthreads();
        // -------- threshold + sym + relu -> sc --------
        float th = 0.1f + sigmoidf_(thadjA[0]) * 0.2f;
        float* dst = sc_out + (size_t)bk * NN2;
        for (int e = t; e < NN2; e += 256){
            int i = e / NN_, j = e - i*NN_;
            float cij = sC[i*LROW + j];
            float cji = sC[j*LROW + i];
            bool kij = (skm[i*4 + (j>>5)] >> (j&31)) & 1u;
            bool kji = (skm[j*4 + (i>>5)] >> (i&31)) & 1u;
            float mij = (fabsf(cij) > th && kij) ? cij : 0.0f;
            float mji = (fabsf(cji) > th && kji) ? cji : 0.0f;
            dst[e] = fmaxf(0.5f*(mij+mji), 0.0f);
        }
    } else {
        // -------- inter --------
        if (t < 128) sW1[t] = eW1[t];
        if (t < 32) sb1[t] = eb1[t];
        if (t >= 128 && t < 256) sW2[t-128] = eW2[t-128];
        if (t < 4) sb2[t] = eb2[t];
        __syncthreads();
        int l = t & 3;
        int il = t >> 2;
        size_t item = (size_t)(blockIdx.x - 512)*64 + il;

        const float* xr = band + item*(NK*NF) + l*NF;
        float s=0,p0=0,p1=0,p2=0,p3=0;
        for (int f = 0; f < NF; ++f){
            float v = xr[f];
            float v1=__shfl_xor(v,1), v2=__shfl_xor(v,2), v3=__shfl_xor(v,3);
            s += v; p0=fmaf(v,v,p0); p1=fmaf(v,v1,p1); p2=fmaf(v,v2,p2); p3=fmaf(v,v3,p3);
        }
        float mu = s*(1.0f/NF);
        float mu1=__shfl_xor(mu,1), mu2=__shfl_xor(mu,2), mu3=__shfl_xor(mu,3);
        float sd = sqrtf(fmaxf(p0 - s*mu, 1e-8f));
        float sd1=__shfl_xor(sd,1), sd2=__shfl_xor(sd,2), sd3=__shfl_xor(sd,3);
        float c0 = CLIP1((p0 - (float)NF*mu*mu )/(sd*sd +1e-8f));
        float c1 = CLIP1((p1 - (float)NF*mu*mu1)/(sd*sd1+1e-8f));
        float c2 = CLIP1((p2 - (float)NF*mu*mu2)/(sd*sd2+1e-8f));
        float c3 = CLIP1((p3 - (float)NF*mu*mu3)/(sd*sd3+1e-8f));

        const float* ar = attn + item*(NS*NK) + l;
        float as=0,q0=0,q1=0,q2=0,q3=0;
        #pragma unroll
        for (int s8 = 0; s8 < NS; ++s8){
            float v = ar[s8*NK];
            float v1=__shfl_xor(v,1), v2=__shfl_xor(v,2), v3=__shfl_xor(v,3);
            as += v; q0=fmaf(v,v,q0); q1=fmaf(v,v1,q1); q2=fmaf(v,v2,q2); q3=fmaf(v,v3,q3);
        }
        float am = as*(1.0f/NS);
        float am1=__shfl_xor(am,1), am2=__shfl_xor(am,2), am3=__shfl_xor(am,3);
        float ad = sqrtf(fmaxf(q0 - as*am, 1e-8f));
        float ad1=__shfl_xor(ad,1), ad2=__shfl_xor(ad,2), ad3=__shfl_xor(ad,3);
        float a0 = CLIP1((q0 - (float)NS*am*am )/(ad*ad +1e-8f));
        float a1 = CLIP1((q1 - (float)NS*am*am1)/(ad*ad1+1e-8f));
        float a2 = CLIP1((q2 - (float)NS*am*am2)/(ad*ad2+1e-8f));
        float a3 = CLIP1((q3 - (float)NS*am*am3)/(ad*ad3+1e-8f));

        float fwv = sigmoidf_(fwp[0]);
        float g0 = fwv*c0 + (1.0f-fwv)*a0;
        float g1 = fwv*c1 + (1.0f-fwv)*a1;
        float g2 = fwv*c2 + (1.0f-fwv)*a2;
        float g3 = fwv*c3 + (1.0f-fwv)*a3;
        float th2 = 0.2f + sigmoidf_(thadjE[0])*0.2f;
        float m0 = (fabsf(g0)>th2)?g0:0.f;
        float m1 = (fabsf(g1)>th2)?g1:0.f;
        float m2 = (fabsf(g2)>th2)?g2:0.f;
        float m3 = (fabsf(g3)>th2)?g3:0.f;

        sMat[il*16 + l*4 + (l^0)] = m0;
        sMat[il*16 + l*4 + (l^1)] = m1;
        sMat[il*16 + l*4 + (l^2)] = m2;
        sMat[il*16 + l*4 + (l^3)] = m3;
        __syncthreads();
        float x0 = fmaxf(0.5f*(sMat[il*16 + l*4 + 0] + sMat[il*16 + 0*4 + l]), 0.f);
        float x1 = fmaxf(0.5f*(sMat[il*16 + l*4 + 1] + sMat[il*16 + 1*4 + l]), 0.f);
        float x2 = fmaxf(0.5f*(sMat[il*16 + l*4 + 2] + sMat[il*16 + 2*4 + l]), 0.f);
        float x3 = fmaxf(0.5f*(sMat[il*16 + l*4 + 3] + sMat[il*16 + 3*4 + l]), 0.f);

        float h[32];
        #pragma unroll
        for (int o = 0; o < 32; ++o){
            float acc = sb1[o];
            acc = fmaf(sW1[o*4+0], x0, acc);
            acc = fmaf(sW1[o*4+1], x1, acc);
            acc = fmaf(sW1[o*4+2], x2, acc);
            acc = fmaf(sW1[o*4+3], x3, acc);
            h[o] = fmaxf(acc, 0.f);
        }
        float o0=sb2[0], o1=sb2[1], o2=sb2[2], o3=sb2[3];
        #pragma unroll
        for (int o = 0; o < 32; ++o){
            float hv = h[o];
            o0 = fmaf(sW2[0*32+o], hv, o0);
            o1 = fmaf(sW2[1*32+o], hv, o1);
            o2 = fmaf(sW2[2*32+o], hv, o2);
            o3 = fmaf(sW2[3*32+o], hv, o3);
        }
        o0 = sigmoidf_(o0); o1 = sigmoidf_(o1); o2 = sigmoidf_(o2); o3 = sigmoidf_(o3);
        __syncthreads();
        sMat[il*16 + l*4 + 0] = o0;
        sMat[il*16 + l*4 + 1] = o1;
        sMat[il*16 + l*4 + 2] = o2;
        sMat[il*16 + l*4 + 3] = o3;
        __syncthreads();
        float y0 = 0.5f*(o0 + sMat[il*16 + 0*4 + l]);
        float y1 = 0.5f*(o1 + sMat[il*16 + 1*4 + l]);
        float y2 = 0.5f*(o2 + sMat[il*16 + 2*4 + l]);
        float y3 = 0.5f*(o3 + sMat[il*16 + 3*4 + l]);
        *(float4*)&inter_out[item*16 + l*4] = make_float4(y0,y1,y2,y3);

        float cnt = ((y0>0.f)?1.f:0.f) + ((y1>0.f)?1.f:0.f) + ((y2>0.f)?1.f:0.f) + ((y3>0.f)?1.f:0.f);
        float sum = y0+y1+y2+y3;
        cnt += __shfl_xor(cnt,1); cnt += __shfl_xor(cnt,2);
        sum += __shfl_xor(sum,1); sum += __shfl_xor(sum,2);
        if (l == 0){
            dens_out[item]  = cnt * (1.0f/16.0f);
            stren_out[item] = sum * (1.0f/16.0f);
        }
    }
}

// ============ K2: fused MLP (H in LDS), 64 rows/block (unchanged r6) ============
__global__ __launch_bounds__(256) void k_mlp(const float* __restrict__ sc,
    const float* __restrict__ W1, const float* __restrict__ b1,
    const float* __restrict__ W2, const float* __restrict__ b2,
    float* __restrict__ intra)
{
    __shared__ float sA_[14848];
    __shared__ float sH[64*68];
    __shared__ float sb1[64];
    __shared__ float sb2[128];
    int t = threadIdx.x;
    int r0 = blockIdx.x * 64;
    float* srow = sA_;
    float* sW1  = sA_ + 7424;
    for (int e4 = t; e4 < 1856; e4 += 256){
        *(float4*)&srow[e4*4] = *(const float4*)&sc[(size_t)r0*116 + e4*4];
        *(float4*)&sW1[e4*4]  = *(const float4*)&W1[e4*4];
    }
    if (t < 64) sb1[t] = b1[t];
    if (t < 128) sb2[t] = (t < NN_) ? b2[t] : 0.0f;
    __syncthreads();
    {
        int rg = t >> 4, og = t & 15;
        float acc[4][4] = {};
        for (int j4 = 0; j4 < 29; ++j4){
            float4 s[4], w[4];
            #pragma unroll
            for (int m = 0; m < 4; ++m) s[m] = *(const float4*)&srow[(rg+16*m)*116 + j4*4];
            #pragma unroll
            for (int n = 0; n < 4; ++n) w[n] = *(const float4*)&sW1[(og+16*n)*116 + j4*4];
            #pragma unroll
            for (int m = 0; m < 4; ++m)
                #pragma unroll
                for (int n = 0; n < 4; ++n)
                    acc[m][n] += dot4_(s[m], w[n]);
        }
        #pragma unroll
        for (int m = 0; m < 4; ++m)
            #pragma unroll
            for (int n = 0; n < 4; ++n)
                sH[(rg+16*m)*68 + og+16*n] = fmaxf(acc[m][n] + sb1[og+16*n], 0.0f);
    }
    __syncthreads();
    float* sW2 = sA_;
    for (int e = t; e < 128*64; e += 256){
        int j = e >> 6, o = e & 63;
        sW2[j*76 + o] = (j < NN_) ? W2[e] : 0.0f;
    }
    __syncthreads();
    {
        int rg = t >> 4, jg = t & 15;
        float acc[4][8] = {};
        for (int o4 = 0; o4 < 16; ++o4){
            float4 h[4], w[8];
            #pragma unroll
            for (int m = 0; m < 4; ++m) h[m] = *(const float4*)&sH[(rg+16*m)*68 + o4*4];
            #pragma unroll
            for (int q = 0; q < 8; ++q) w[q] = *(const float4*)&sW2[(jg+16*q)*76 + o4*4];
            #pragma unroll
            for (int m = 0; m < 4; ++m)
                #pragma unroll
                for (int q = 0; q < 8; ++q)
                    acc[m][q] += dot4_(h[m], w[q]);
        }
        #pragma unroll
        for (int m = 0; m < 4; ++m){
            int row = r0 + rg + 16*m;
            #pragma unroll
            for (int q = 0; q < 8; ++q){
                int j = jg + 16*q;
                if (j < NN_)
                    intra[(size_t)row*116 + j] = sigmoidf_(acc[m][q] + sb2[j]);
            }
        }
    }
}

// ============ K3: sym+deg/clus (4 sub-bands in LDS) + gstats + graphlin ============
__global__ __launch_bounds__(512) void k_symg(const float* __restrict__ intra,
    const float* __restrict__ dens, const float* __restrict__ stren,
    const float* __restrict__ band, const float* __restrict__ Wc,
    const float* __restrict__ bc, float* __restrict__ ia,
    float* __restrict__ gfo, float* __restrict__ aux)
{
    __shared__ float sm[NN_*LROW];        // 54.3 KB
    __shared__ float sdeg[KN], sclus[KN];
    __shared__ float sPs[18*14*4], sPq[18*14*4];
    __shared__ float sGf[152];
    __shared__ float sA[8], sB[8];
    int b = blockIdx.x, t = threadIdx.x;

    for (int k = 0; k < NK; ++k){
        const float* src = intra + ((size_t)(b*NK + k))*NN2;
        for (int e = t; e < NN2; e += 512){
            int i = e / NN_, j = e - i*NN_;
            sm[i*LROW + j] = src[e];
        }
        __syncthreads();
        float* dst = ia + ((size_t)(b*NK + k))*NN2;
        for (int e = t; e < NN2; e += 512){
            int i = e / NN_, j = e - i*NN_;
            dst[e] = 0.5f*(sm[i*LROW + j] + sm[j*LROW + i]);
        }
        if (t < NN_*4){
            int r = t >> 2, q = t & 3;
            float tri = 0.f, dg = 0.f;
            for (int jj = 0; jj < 29; ++jj){
                int j = q*29 + jj;
                float v = 0.5f*(sm[r*LROW+j] + sm[j*LROW+r]);
                tri = fmaf(v, v, tri);
                dg += (v > 0.f) ? 1.f : 0.f;
            }
            tri += __shfl_xor(tri,1); tri += __shfl_xor(tri,2);
            dg  += __shfl_xor(dg,1);  dg  += __shfl_xor(dg,2);
            if (q == 0){
                sdeg[k*NN_ + r]  = dg;
                sclus[k*NN_ + r] = tri / (dg*dg + 1e-8f);
            }
        }
        __syncthreads();
    }

    // band mean/std per f
    if (t < 252){
        int fq = t % 18, g = t / 18;
        float4 s = make_float4(0,0,0,0), q = make_float4(0,0,0,0);
        const float* base = band + (size_t)b*(KN*NF);
        for (int nk = g; nk < KN; nk += 14){
            float4 v = *(const float4*)&base[nk*NF + fq*4];
            s.x += v.x; s.y += v.y; s.z += v.z; s.w += v.w;
            q.x = fmaf(v.x,v.x,q.x); q.y = fmaf(v.y,v.y,q.y);
            q.z = fmaf(v.z,v.z,q.z); q.w = fmaf(v.w,v.w,q.w);
        }
        int idx = (fq*14 + g)*4;
        *(float4*)&sPs[idx] = s;
        *(float4*)&sPq[idx] = q;
    }
    __syncthreads();
    if (t < NF){
        int fq = t >> 2, e = t & 3;
        float S = 0.f, Q = 0.f;
        for (int g = 0; g < 14; ++g){ S += sPs[(fq*14+g)*4+e]; Q += sPq[(fq*14+g)*4+e]; }
        float mean = S * (1.0f/(float)KN);
        float var = fmaxf((Q - S*mean)/((float)KN - 1.0f), 0.0f);
        sGf[t] = mean;
        sGf[NF + t] = sqrtf(var);
    }
    __syncthreads();

    // deg stats
    float s = (t < KN) ? sdeg[t] : 0.f;
    float ss = s*s;
    #pragma unroll
    for (int d = 1; d < 64; d <<= 1){ s += __shfl_xor(s,d); ss += __shfl_xor(ss,d); }
    if ((t & 63) == 0){ sA[t>>6] = s; sB[t>>6] = ss; }
    __syncthreads();
    if (t == 0){
        float S0=0.f, S1=0.f;
        #pragma unroll
        for (int w = 0; w < 8; ++w){ S0 += sA[w]; S1 += sB[w]; }
        float Mv = (float)KN, mean = S0/Mv;
        float var = fmaxf((S1 - S0*mean)/(Mv - 1.0f), 0.0f);
        sGf[144] = mean; sGf[145] = sqrtf(var);
        aux[b] = S0;
    }
    __syncthreads();

    // clus stats
    s = (t < KN) ? sclus[t] : 0.f;
    ss = s*s;
    #pragma unroll
    for (int d = 1; d < 64; d <<= 1){ s += __shfl_xor(s,d); ss += __shfl_xor(ss,d); }
    if ((t & 63) == 0){ sA[t>>6] = s; sB[t>>6] = ss; }
    __syncthreads();
    if (t == 0){
        float S0=0.f, S1=0.f;
        #pragma unroll
        for (int w = 0; w < 8; ++w){ S0 += sA[w]; S1 += sB[w]; }
        float Mv = (float)KN, mean = S0/Mv;
        float var = fmaxf((S1 - S0*mean)/(Mv - 1.0f), 0.0f);
        sGf[146] = mean; sGf[147] = sqrtf(var);
    }
    __syncthreads();

    // dens/stren means
    s = (t < NN_) ? dens[(size_t)b*NN_ + t] : 0.f;
    ss = (t < NN_) ? stren[(size_t)b*NN_ + t] : 0.f;
    #pragma unroll
    for (int d = 1; d < 64; d <<= 1){ s += __shfl_xor(s,d); ss += __shfl_xor(ss,d); }
    if ((t & 63) == 0){ sA[t>>6] = s; sB[t>>6] = ss; }
    __syncthreads();
    if (t == 0){
        float S0=0.f, S1=0.f;
        #pragma unroll
        for (int w = 0; w < 8; ++w){ S0 += sA[w]; S1 += sB[w]; }
        sGf[148] = S0 / (float)NN_;
        sGf[149] = S1 / (float)NN_;
        aux[128 + b] = S0 * 16.0f;
    }
    __syncthreads();

    if (t < 128){
        float acc = bc[t];
        const float* w = Wc + (size_t)t*150;
        for (int c = 0; c < 150; ++c) acc = fmaf(sGf[c], w[c], acc);
        gfo[(size_t)b*128 + t] = fmaxf(acc, 0.f);
    }
}

// ---------------- sparsity (fallback standalone) ----------------
__global__ __launch_bounds__(64) void k_sparsity(const float* __restrict__ aux, float* __restrict__ out3)
{
    int t = threadIdx.x;
    float a = aux[t] + aux[64 + t];
    float c = aux[128 + t] + aux[192 + t];
    #pragma unroll
    for (int d = 1; d < 64; d <<= 1){ a += __shfl_xor(a,d); c += __shfl_xor(c,d); }
    if (t == 0){
        const float it = 6889472.0f, jt = 237568.0f;
        float isp = 1.0f - a/it;
        float jsp = 1.0f - c/jt;
        out3[0] = isp; out3[1] = jsp;
        out3[2] = (isp*it + jsp*jt)/(it + jt);
    }
}

// ============ K4: unified + node features (grid-stride) + optional sparsity ============
#define UNQ (SZ_UNI/4)       // 6889472 float4 quads
#define NFQ (SZ_NF/4)        // 1069056 float4 quads
__global__ __launch_bounds__(256) void k_uninf(const float* __restrict__ intra_adj,
    const float* __restrict__ inter_adj, const float* __restrict__ band,
    const float* __restrict__ aux, float* __restrict__ uni, float* __restrict__ nf,
    float* __restrict__ sp, int do_sp)
{
    if (do_sp && blockIdx.x == 0 && threadIdx.x < 64){
        int t = threadIdx.x;
        float a = aux[t] + aux[64 + t];
        float c = aux[128 + t] + aux[192 + t];
        #pragma unroll
        for (int d = 1; d < 64; d <<= 1){ a += __shfl_xor(a,d); c += __shfl_xor(c,d); }
        if (t == 0){
            const float it = 6889472.0f, jt = 237568.0f;
            float isp = 1.0f - a/it;
            float jsp = 1.0f - c/jt;
            sp[0] = isp; sp[1] = jsp;
            sp[2] = (isp*it + jsp*jt)/(it + jt);
        }
    }
    int gid = blockIdx.x*256 + threadIdx.x;
    int gsz = gridDim.x*256;
    for (int q = gid; q < UNQ; q += gsz){
        int row = q / 116;
        int cq  = q - row*116;
        int b = row / KN;
        int p = row - b*KN;
        int k1 = p / NN_;
        int i  = p - k1*NN_;
        int k2 = cq / 29;
        int j0 = cq*4 - k2*NN_;
        float4 v;
        if (k2 == k1){
            v = *(const float4*)&intra_adj[(((size_t)b*NK + k1)*NN_ + i)*NN_ + j0];
        } else {
            int d = i - j0;
            float val = 0.f;
            if (d >= 0 && d < 4)
                val = inter_adj[(((size_t)b*NN_ + i)*NK + k1)*NK + k2];
            v.x = (d==0)?val:0.f;
            v.y = (d==1)?val:0.f;
            v.z = (d==2)?val:0.f;
            v.w = (d==3)?val:0.f;
        }
        *(float4*)&uni[(size_t)q*4] = v;
    }
    for (int q = gid; q < NFQ; q += gsz){
        int fq = q % 18;
        int rest = q / 18;
        int b = rest / KN;
        int p = rest - b*KN;
        int k = p / NN_;
        int n = p - k*NN_;
        float4 v = *(const float4*)&band[(((size_t)b*NN_ + n)*NK + k)*NF + fq*4];
        *(float4*)&nf[(size_t)q*4] = v;
    }
}

extern "C" void kernel_launch(void* const* d_in, const int* in_sizes, int n_in,
                              void* d_out, int out_size, void* d_ws, size_t ws_size,
                              hipStream_t stream)
{
    const float* band = (const float*)d_in[0];
    const float* attn = (const float*)d_in[1];
    const float* thA  = (const float*)d_in[2];
    const float* thE  = (const float*)d_in[3];
    const float* fw   = (const float*)d_in[4];
    const float* iW1  = (const float*)d_in[5];
    const float* ib1  = (const float*)d_in[6];
    const float* iW2  = (const float*)d_in[7];
    const float* ib2  = (const float*)d_in[8];
    const float* eW1  = (const float*)d_in[9];
    const float* eb1  = (const float*)d_in[10];
    const float* eW2  = (const float*)d_in[11];
    const float* eb2  = (const float*)d_in[12];
    const float* cW   = (const float*)d_in[13];
    const float* cb   = (const float*)d_in[14];

    float* out = (float*)d_out;
    float* uni = out + OFF_UNI;
    float* nf  = out + OFF_NF;
    float* gfo = out + OFF_GF;
    float* ia  = out + OFF_IA;
    float* ie  = out + OFF_IE;
    float* sp  = out + OFF_SP;

    float* scr_sc    = uni + SCR_SC;
    float* scr_dens  = uni + SCR_DENS;
    float* scr_stren = uni + SCR_STREN;

    int ws_ok = (ws_size >= 256*sizeof(float));
    float* aux = ws_ok ? (float*)d_ws : (uni + SCR_AUX);

    k_front<<<512 + BN/64, 256, 0, stream>>>(band, attn, thA, thE, fw,
                                             eW1, eb1, eW2, eb2,
                                             scr_sc, ie, scr_dens, scr_stren);
    k_mlp<<<ROWS/64, 256, 0, stream>>>(scr_sc, iW1, ib1, iW2, ib2, scr_sc);
    k_symg<<<NB, 512, 0, stream>>>(scr_sc, scr_dens, scr_stren, band, cW, cb,
                                   ia, gfo, aux);
    if (!ws_ok)
        k_sparsity<<<1, 64, 0, stream>>>(aux, sp);
    k_uninf<<<2048, 256, 0, stream>>>(ia, ie, band, aux, uni, nf, sp, ws_ok ? 1 : 0);
}

// Round 9
// 163.504 us; speedup vs baseline: 1.1062x; 1.1062x over previous
//
#include <hip/hip_runtime.h>
#include <math.h>

#define NB 128     // B
#define NN_ 116    // N
#define NK 4       // K
#define NF 72      // F
#define NS 8       // S
#define TOPK 10

#define BK (NB*NK)            // 512
#define BN (NB*NN_)           // 14848
#define NN2 (NN_*NN_)         // 13456
#define KN (NK*NN_)           // 464
#define ROWS (BK*NN_)         // 59392
#define LROW 117              // padded LDS row stride

// output section offsets (floats)
#define OFF_UNI 0
#define SZ_UNI (NB*KN*KN)                 // 27557888
#define OFF_NF (OFF_UNI + SZ_UNI)
#define SZ_NF (NB*KN*NF)                  // 4276224
#define OFF_GF (OFF_NF + SZ_NF)
#define SZ_GF (NB*128)
#define OFF_IA (OFF_GF + SZ_GF)
#define SZ_IA (NB*NK*NN_*NN_)             // 6889472
#define OFF_IE (OFF_IA + SZ_IA)
#define SZ_IE (NB*NN_*NK*NK)              // 237568
#define OFF_SP (OFF_IE + SZ_IE)

// scratch inside the unified region (consumed before k_uninf overwrites it)
#define SCR_SC 0                          // sc -> intra in-place
#define SCR_CORR (SCR_SC + SZ_IA)
#define SCR_DENS (SCR_CORR + SZ_IA)       // BN
#define SCR_STREN (SCR_DENS + BN)         // BN
#define SCR_AUX (SCR_STREN + BN)          // 2*NB (fallback)

__device__ __forceinline__ float sigmoidf_(float x){ return 1.0f/(1.0f+expf(-x)); }
__device__ __forceinline__ float dot4_(float4 a, float4 b){
    return fmaf(a.x,b.x, fmaf(a.y,b.y, fmaf(a.z,b.z, a.w*b.w)));
}
#define CLIP1(x) fminf(1.0f, fmaxf(-1.0f, (x)))

// ---------------- FAT1: blocks <512 = corr; blocks >=512 = inter (r7 proven) ----------------
__global__ __launch_bounds__(256, 1) void k_corr_inter(const float* __restrict__ band,
    const float* __restrict__ attn, const float* __restrict__ thadj2,
    const float* __restrict__ fwp,
    const float* __restrict__ eW1, const float* __restrict__ eb1,
    const float* __restrict__ eW2, const float* __restrict__ eb2,
    float* __restrict__ corr_out, float* __restrict__ inter_out,
    float* __restrict__ dens_out, float* __restrict__ stren_out)
{
    __shared__ float sx[NF*120];
    __shared__ float smu[120], srs[120];
    __shared__ float sW1[128], sb1[32], sW2[128], sb2[4];
    __shared__ float sMat[256*4];
    int t = threadIdx.x;
    if (blockIdx.x < 512){
        int bk = blockIdx.x;
        int b = bk >> 2, k = bk & 3;
        const float* xin = band + ((size_t)b*NN_*NK + k)*NF;
        for (int e = t; e < NN_*NF; e += 256){
            int n = e / NF, f = e - n*NF;
            sx[f*120 + n] = xin[(size_t)n*NK*NF + f];
        }
        for (int e = t; e < NF*4; e += 256)
            sx[(e>>2)*120 + NN_ + (e&3)] = 0.0f;
        __syncthreads();
        if (t < NN_){
            float s = 0.f, ss = 0.f;
            for (int f = 0; f < NF; ++f){ float v = sx[f*120+t]; s += v; ss += v*v; }
            float mu = s * (1.0f/NF);
            float sd = sqrtf(fmaxf(ss - s*mu, 1e-8f));
            smu[t] = mu; srs[t] = 1.0f/sd;
        }
        __syncthreads();
        for (int e = t; e < NF*NN_; e += 256){
            int f = e / NN_, n = e - f*NN_;
            sx[f*120+n] = (sx[f*120+n] - smu[n]) * srs[n];
        }
        __syncthreads();
        float* dst = corr_out + (size_t)bk * NN2;
        if (t < 225){
            int ti = t / 15, tj = t - ti*15;
            int i0 = ti*8, j0 = tj*8;
            float acc[8][8] = {};
            for (int f = 0; f < NF; ++f){
                const float4 a0 = *(const float4*)&sx[f*120 + i0];
                const float4 a1 = *(const float4*)&sx[f*120 + i0 + 4];
                const float4 c0 = *(const float4*)&sx[f*120 + j0];
                const float4 c1 = *(const float4*)&sx[f*120 + j0 + 4];
                float av[8] = {a0.x,a0.y,a0.z,a0.w,a1.x,a1.y,a1.z,a1.w};
                float cv[8] = {c0.x,c0.y,c0.z,c0.w,c1.x,c1.y,c1.z,c1.w};
                #pragma unroll
                for (int r = 0; r < 8; ++r)
                    #pragma unroll
                    for (int c = 0; c < 8; ++c)
                        acc[r][c] = fmaf(av[r], cv[c], acc[r][c]);
            }
            #pragma unroll
            for (int r = 0; r < 8; ++r){
                int i = i0 + r;
                if (i < NN_){
                    float4 v0;
                    v0.x = CLIP1(acc[r][0]); v0.y = CLIP1(acc[r][1]);
                    v0.z = CLIP1(acc[r][2]); v0.w = CLIP1(acc[r][3]);
                    *(float4*)&dst[i*NN_ + j0] = v0;
                    if (j0 + 4 <= 112){
                        float4 v1;
                        v1.x = CLIP1(acc[r][4]); v1.y = CLIP1(acc[r][5]);
                        v1.z = CLIP1(acc[r][6]); v1.w = CLIP1(acc[r][7]);
                        *(float4*)&dst[i*NN_ + j0 + 4] = v1;
                    }
                }
            }
        }
    } else {
        if (t < 128) sW1[t] = eW1[t];
        if (t < 32) sb1[t] = eb1[t];
        if (t >= 128 && t < 256) sW2[t-128] = eW2[t-128];
        if (t < 4) sb2[t] = eb2[t];
        __syncthreads();
        int l = t & 3;
        int il = t >> 2;
        size_t item = (size_t)(blockIdx.x - 512)*64 + il;

        const float* xr = band + item*(NK*NF) + l*NF;
        float s=0,p0=0,p1=0,p2=0,p3=0;
        for (int f = 0; f < NF; ++f){
            float v = xr[f];
            float v1=__shfl_xor(v,1), v2=__shfl_xor(v,2), v3=__shfl_xor(v,3);
            s += v; p0=fmaf(v,v,p0); p1=fmaf(v,v1,p1); p2=fmaf(v,v2,p2); p3=fmaf(v,v3,p3);
        }
        float mu = s*(1.0f/NF);
        float mu1=__shfl_xor(mu,1), mu2=__shfl_xor(mu,2), mu3=__shfl_xor(mu,3);
        float sd = sqrtf(fmaxf(p0 - s*mu, 1e-8f));
        float sd1=__shfl_xor(sd,1), sd2=__shfl_xor(sd,2), sd3=__shfl_xor(sd,3);
        float c0 = CLIP1((p0 - (float)NF*mu*mu )/(sd*sd +1e-8f));
        float c1 = CLIP1((p1 - (float)NF*mu*mu1)/(sd*sd1+1e-8f));
        float c2 = CLIP1((p2 - (float)NF*mu*mu2)/(sd*sd2+1e-8f));
        float c3 = CLIP1((p3 - (float)NF*mu*mu3)/(sd*sd3+1e-8f));

        const float* ar = attn + item*(NS*NK) + l;
        float as=0,q0=0,q1=0,q2=0,q3=0;
        #pragma unroll
        for (int s8 = 0; s8 < NS; ++s8){
            float v = ar[s8*NK];
            float v1=__shfl_xor(v,1), v2=__shfl_xor(v,2), v3=__shfl_xor(v,3);
            as += v; q0=fmaf(v,v,q0); q1=fmaf(v,v1,q1); q2=fmaf(v,v2,q2); q3=fmaf(v,v3,q3);
        }
        float am = as*(1.0f/NS);
        float am1=__shfl_xor(am,1), am2=__shfl_xor(am,2), am3=__shfl_xor(am,3);
        float ad = sqrtf(fmaxf(q0 - as*am, 1e-8f));
        float ad1=__shfl_xor(ad,1), ad2=__shfl_xor(ad,2), ad3=__shfl_xor(ad,3);
        float a0 = CLIP1((q0 - (float)NS*am*am )/(ad*ad +1e-8f));
        float a1 = CLIP1((q1 - (float)NS*am*am1)/(ad*ad1+1e-8f));
        float a2 = CLIP1((q2 - (float)NS*am*am2)/(ad*ad2+1e-8f));
        float a3 = CLIP1((q3 - (float)NS*am*am3)/(ad*ad3+1e-8f));

        float fwv = sigmoidf_(fwp[0]);
        float g0 = fwv*c0 + (1.0f-fwv)*a0;
        float g1 = fwv*c1 + (1.0f-fwv)*a1;
        float g2 = fwv*c2 + (1.0f-fwv)*a2;
        float g3 = fwv*c3 + (1.0f-fwv)*a3;
        float th2 = 0.2f + sigmoidf_(thadj2[0])*0.2f;
        float m0 = (fabsf(g0)>th2)?g0:0.f;
        float m1 = (fabsf(g1)>th2)?g1:0.f;
        float m2 = (fabsf(g2)>th2)?g2:0.f;
        float m3 = (fabsf(g3)>th2)?g3:0.f;

        sMat[il*16 + l*4 + (l^0)] = m0;
        sMat[il*16 + l*4 + (l^1)] = m1;
        sMat[il*16 + l*4 + (l^2)] = m2;
        sMat[il*16 + l*4 + (l^3)] = m3;
        __syncthreads();
        float x0 = fmaxf(0.5f*(sMat[il*16 + l*4 + 0] + sMat[il*16 + 0*4 + l]), 0.f);
        float x1 = fmaxf(0.5f*(sMat[il*16 + l*4 + 1] + sMat[il*16 + 1*4 + l]), 0.f);
        float x2 = fmaxf(0.5f*(sMat[il*16 + l*4 + 2] + sMat[il*16 + 2*4 + l]), 0.f);
        float x3 = fmaxf(0.5f*(sMat[il*16 + l*4 + 3] + sMat[il*16 + 3*4 + l]), 0.f);

        float h[32];
        #pragma unroll
        for (int o = 0; o < 32; ++o){
            float acc = sb1[o];
            acc = fmaf(sW1[o*4+0], x0, acc);
            acc = fmaf(sW1[o*4+1], x1, acc);
            acc = fmaf(sW1[o*4+2], x2, acc);
            acc = fmaf(sW1[o*4+3], x3, acc);
            h[o] = fmaxf(acc, 0.f);
        }
        float o0=sb2[0], o1=sb2[1], o2=sb2[2], o3=sb2[3];
        #pragma unroll
        for (int o = 0; o < 32; ++o){
            float hv = h[o];
            o0 = fmaf(sW2[0*32+o], hv, o0);
            o1 = fmaf(sW2[1*32+o], hv, o1);
            o2 = fmaf(sW2[2*32+o], hv, o2);
            o3 = fmaf(sW2[3*32+o], hv, o3);
        }
        o0 = sigmoidf_(o0); o1 = sigmoidf_(o1); o2 = sigmoidf_(o2); o3 = sigmoidf_(o3);
        __syncthreads();
        sMat[il*16 + l*4 + 0] = o0;
        sMat[il*16 + l*4 + 1] = o1;
        sMat[il*16 + l*4 + 2] = o2;
        sMat[il*16 + l*4 + 3] = o3;
        __syncthreads();
        float y0 = 0.5f*(o0 + sMat[il*16 + 0*4 + l]);
        float y1 = 0.5f*(o1 + sMat[il*16 + 1*4 + l]);
        float y2 = 0.5f*(o2 + sMat[il*16 + 2*4 + l]);
        float y3 = 0.5f*(o3 + sMat[il*16 + 3*4 + l]);
        *(float4*)&inter_out[item*16 + l*4] = make_float4(y0,y1,y2,y3);

        float cnt = ((y0>0.f)?1.f:0.f) + ((y1>0.f)?1.f:0.f) + ((y2>0.f)?1.f:0.f) + ((y3>0.f)?1.f:0.f);
        float sum = y0+y1+y2+y3;
        cnt += __shfl_xor(cnt,1); cnt += __shfl_xor(cnt,2);
        sum += __shfl_xor(sum,1); sum += __shfl_xor(sum,2);
        if (l == 0){
            dens_out[item]  = cnt * (1.0f/16.0f);
            stren_out[item] = sum * (1.0f/16.0f);
        }
    }
}

// ---------------- K1b: top-k (4 thr/row) + threshold + sym -> sc (r7 proven) ----------------
__global__ __launch_bounds__(512) void k_topk_mask(const float* __restrict__ corr_in,
    const float* __restrict__ thadj, float* __restrict__ sc_out)
{
    __shared__ float sc_[NN_*LROW];
    __shared__ unsigned skm[NN_*4];
    __shared__ unsigned stop[464*10];
    int bk = blockIdx.x;
    int t = threadIdx.x;
    const float* src = corr_in + (size_t)bk*NN2;
    for (int e = t; e < NN2; e += 512){
        int i = e / NN_, j = e - i*NN_;
        sc_[i*LROW + j] = src[e];
    }
    __syncthreads();
    if (t < NN_*4){
        int r = t >> 2, q = t & 3;
        const float* row = &sc_[r*LROW + q*29];
        int jbase = q*29;
        unsigned tv[TOPK];
        #pragma unroll
        for (int p = 0; p < TOPK; ++p) tv[p] = 0u;
        for (int jj = 0; jj < 29; ++jj){
            float c = fabsf(row[jj]);
            unsigned u = (__float_as_uint(c) & 0xFFFFFF80u) | (unsigned)(127 - (jbase + jj));
            #pragma unroll
            for (int p = 0; p < TOPK; ++p){
                unsigned old = tv[p];
                bool gt = u > old;
                tv[p] = gt ? u : old;
                u = gt ? old : u;
            }
        }
        #pragma unroll
        for (int p = 0; p < TOPK; ++p) stop[t*10 + p] = tv[p];
    }
    __syncthreads();
    if (t < NN_){
        const unsigned* L0 = &stop[(4*t+0)*10];
        const unsigned* L1 = &stop[(4*t+1)*10];
        const unsigned* L2 = &stop[(4*t+2)*10];
        const unsigned* L3 = &stop[(4*t+3)*10];
        int i0=0, i1=0, i2=0, i3=0;
        unsigned m0=0,m1=0,m2=0,m3=0;
        #pragma unroll
        for (int p = 0; p < TOPK; ++p){
            unsigned u0 = L0[i0], u1 = L1[i1], u2 = L2[i2], u3 = L3[i3];
            unsigned ua = u0 > u1 ? u0 : u1;
            unsigned ub = u2 > u3 ? u2 : u3;
            unsigned u  = ua > ub ? ua : ub;
            if (u == u0) ++i0; else if (u == u1) ++i1; else if (u == u2) ++i2; else ++i3;
            int j = 127 - (int)(u & 127u);
            unsigned bit = 1u << (j & 31);
            int w = j >> 5;
            if (w == 0) m0 |= bit; else if (w == 1) m1 |= bit; else if (w == 2) m2 |= bit; else m3 |= bit;
        }
        skm[t*4+0]=m0; skm[t*4+1]=m1; skm[t*4+2]=m2; skm[t*4+3]=m3;
    }
    __syncthreads();
    float th = 0.1f + sigmoidf_(thadj[0]) * 0.2f;
    float* dst = sc_out + (size_t)bk * NN2;
    for (int e = t; e < NN2; e += 512){
        int i = e / NN_, j = e - i*NN_;
        float cij = sc_[i*LROW + j];
        float cji = sc_[j*LROW + i];
        bool kij = (skm[i*4 + (j>>5)] >> (j&31)) & 1u;
        bool kji = (skm[j*4 + (i>>5)] >> (i&31)) & 1u;
        float mij = (fabsf(cij) > th && kij) ? cij : 0.0f;
        float mji = (fabsf(cji) > th && kji) ? cji : 0.0f;
        dst[e] = fmaxf(0.5f*(mij+mji), 0.0f);
    }
}

// ---------------- K2: fused MLP (H in LDS), 64 rows/block (r6 proven) ----------------
__global__ __launch_bounds__(256) void k_mlp(const float* __restrict__ sc,
    const float* __restrict__ W1, const float* __restrict__ b1,
    const float* __restrict__ W2, const float* __restrict__ b2,
    float* __restrict__ intra)
{
    __shared__ float sA_[14848];
    __shared__ float sH[64*68];
    __shared__ float sb1[64];
    __shared__ float sb2[128];
    int t = threadIdx.x;
    int r0 = blockIdx.x * 64;
    float* srow = sA_;
    float* sW1  = sA_ + 7424;
    for (int e4 = t; e4 < 1856; e4 += 256){
        *(float4*)&srow[e4*4] = *(const float4*)&sc[(size_t)r0*116 + e4*4];
        *(float4*)&sW1[e4*4]  = *(const float4*)&W1[e4*4];
    }
    if (t < 64) sb1[t] = b1[t];
    if (t < 128) sb2[t] = (t < NN_) ? b2[t] : 0.0f;
    __syncthreads();
    {
        int rg = t >> 4, og = t & 15;
        float acc[4][4] = {};
        for (int j4 = 0; j4 < 29; ++j4){
            float4 s[4], w[4];
            #pragma unroll
            for (int m = 0; m < 4; ++m) s[m] = *(const float4*)&srow[(rg+16*m)*116 + j4*4];
            #pragma unroll
            for (int n = 0; n < 4; ++n) w[n] = *(const float4*)&sW1[(og+16*n)*116 + j4*4];
            #pragma unroll
            for (int m = 0; m < 4; ++m)
                #pragma unroll
                for (int n = 0; n < 4; ++n)
                    acc[m][n] += dot4_(s[m], w[n]);
        }
        #pragma unroll
        for (int m = 0; m < 4; ++m)
            #pragma unroll
            for (int n = 0; n < 4; ++n)
                sH[(rg+16*m)*68 + og+16*n] = fmaxf(acc[m][n] + sb1[og+16*n], 0.0f);
    }
    __syncthreads();
    float* sW2 = sA_;
    for (int e = t; e < 128*64; e += 256){
        int j = e >> 6, o = e & 63;
        sW2[j*76 + o] = (j < NN_) ? W2[e] : 0.0f;
    }
    __syncthreads();
    {
        int rg = t >> 4, jg = t & 15;
        float acc[4][8] = {};
        for (int o4 = 0; o4 < 16; ++o4){
            float4 h[4], w[8];
            #pragma unroll
            for (int m = 0; m < 4; ++m) h[m] = *(const float4*)&sH[(rg+16*m)*68 + o4*4];
            #pragma unroll
            for (int q = 0; q < 8; ++q) w[q] = *(const float4*)&sW2[(jg+16*q)*76 + o4*4];
            #pragma unroll
            for (int m = 0; m < 4; ++m)
                #pragma unroll
                for (int q = 0; q < 8; ++q)
                    acc[m][q] += dot4_(h[m], w[q]);
        }
        #pragma unroll
        for (int m = 0; m < 4; ++m){
            int row = r0 + rg + 16*m;
            #pragma unroll
            for (int q = 0; q < 8; ++q){
                int j = jg + 16*q;
                if (j < NN_)
                    intra[(size_t)row*116 + j] = sigmoidf_(acc[m][q] + sb2[j]);
            }
        }
    }
}

// ============ K3: sym+deg/clus (4 sub-bands in LDS) + gstats + graphlin (r8 proven) ============
__global__ __launch_bounds__(512) void k_symg(const float* __restrict__ intra,
    const float* __restrict__ dens, const float* __restrict__ stren,
    const float* __restrict__ band, const float* __restrict__ Wc,
    const float* __restrict__ bc, float* __restrict__ ia,
    float* __restrict__ gfo, float* __restrict__ aux)
{
    __shared__ float sm[NN_*LROW];
    __shared__ float sdeg[KN], sclus[KN];
    __shared__ float sPs[18*14*4], sPq[18*14*4];
    __shared__ float sGf[152];
    __shared__ float sA[8], sB[8];
    int b = blockIdx.x, t = threadIdx.x;

    for (int k = 0; k < NK; ++k){
        const float* src = intra + ((size_t)(b*NK + k))*NN2;
        for (int e = t; e < NN2; e += 512){
            int i = e / NN_, j = e - i*NN_;
            sm[i*LROW + j] = src[e];
        }
        __syncthreads();
        float* dst = ia + ((size_t)(b*NK + k))*NN2;
        for (int e = t; e < NN2; e += 512){
            int i = e / NN_, j = e - i*NN_;
            dst[e] = 0.5f*(sm[i*LROW + j] + sm[j*LROW + i]);
        }
        if (t < NN_*4){
            int r = t >> 2, q = t & 3;
            float tri = 0.f, dg = 0.f;
            for (int jj = 0; jj < 29; ++jj){
                int j = q*29 + jj;
                float v = 0.5f*(sm[r*LROW+j] + sm[j*LROW+r]);
                tri = fmaf(v, v, tri);
                dg += (v > 0.f) ? 1.f : 0.f;
            }
            tri += __shfl_xor(tri,1); tri += __shfl_xor(tri,2);
            dg  += __shfl_xor(dg,1);  dg  += __shfl_xor(dg,2);
            if (q == 0){
                sdeg[k*NN_ + r]  = dg;
                sclus[k*NN_ + r] = tri / (dg*dg + 1e-8f);
            }
        }
        __syncthreads();
    }

    if (t < 252){
        int fq = t % 18, g = t / 18;
        float4 s = make_float4(0,0,0,0), q = make_float4(0,0,0,0);
        const float* base = band + (size_t)b*(KN*NF);
        for (int nk = g; nk < KN; nk += 14){
            float4 v = *(const float4*)&base[nk*NF + fq*4];
            s.x += v.x; s.y += v.y; s.z += v.z; s.w += v.w;
            q.x = fmaf(v.x,v.x,q.x); q.y = fmaf(v.y,v.y,q.y);
            q.z = fmaf(v.z,v.z,q.z); q.w = fmaf(v.w,v.w,q.w);
        }
        int idx = (fq*14 + g)*4;
        *(float4*)&sPs[idx] = s;
        *(float4*)&sPq[idx] = q;
    }
    __syncthreads();
    if (t < NF){
        int fq = t >> 2, e = t & 3;
        float S = 0.f, Q = 0.f;
        for (int g = 0; g < 14; ++g){ S += sPs[(fq*14+g)*4+e]; Q += sPq[(fq*14+g)*4+e]; }
        float mean = S * (1.0f/(float)KN);
        float var = fmaxf((Q - S*mean)/((float)KN - 1.0f), 0.0f);
        sGf[t] = mean;
        sGf[NF + t] = sqrtf(var);
    }
    __syncthreads();

    float s = (t < KN) ? sdeg[t] : 0.f;
    float ss = s*s;
    #pragma unroll
    for (int d = 1; d < 64; d <<= 1){ s += __shfl_xor(s,d); ss += __shfl_xor(ss,d); }
    if ((t & 63) == 0){ sA[t>>6] = s; sB[t>>6] = ss; }
    __syncthreads();
    if (t == 0){
        float S0=0.f, S1=0.f;
        #pragma unroll
        for (int w = 0; w < 8; ++w){ S0 += sA[w]; S1 += sB[w]; }
        float Mv = (float)KN, mean = S0/Mv;
        float var = fmaxf((S1 - S0*mean)/(Mv - 1.0f), 0.0f);
        sGf[144] = mean; sGf[145] = sqrtf(var);
        aux[b] = S0;
    }
    __syncthreads();

    s = (t < KN) ? sclus[t] : 0.f;
    ss = s*s;
    #pragma unroll
    for (int d = 1; d < 64; d <<= 1){ s += __shfl_xor(s,d); ss += __shfl_xor(ss,d); }
    if ((t & 63) == 0){ sA[t>>6] = s; sB[t>>6] = ss; }
    __syncthreads();
    if (t == 0){
        float S0=0.f, S1=0.f;
        #pragma unroll
        for (int w = 0; w < 8; ++w){ S0 += sA[w]; S1 += sB[w]; }
        float Mv = (float)KN, mean = S0/Mv;
        float var = fmaxf((S1 - S0*mean)/(Mv - 1.0f), 0.0f);
        sGf[146] = mean; sGf[147] = sqrtf(var);
    }
    __syncthreads();

    s = (t < NN_) ? dens[(size_t)b*NN_ + t] : 0.f;
    ss = (t < NN_) ? stren[(size_t)b*NN_ + t] : 0.f;
    #pragma unroll
    for (int d = 1; d < 64; d <<= 1){ s += __shfl_xor(s,d); ss += __shfl_xor(ss,d); }
    if ((t & 63) == 0){ sA[t>>6] = s; sB[t>>6] = ss; }
    __syncthreads();
    if (t == 0){
        float S0=0.f, S1=0.f;
        #pragma unroll
        for (int w = 0; w < 8; ++w){ S0 += sA[w]; S1 += sB[w]; }
        sGf[148] = S0 / (float)NN_;
        sGf[149] = S1 / (float)NN_;
        aux[128 + b] = S0 * 16.0f;
    }
    __syncthreads();

    if (t < 128){
        float acc = bc[t];
        const float* w = Wc + (size_t)t*150;
        for (int c = 0; c < 150; ++c) acc = fmaf(sGf[c], w[c], acc);
        gfo[(size_t)b*128 + t] = fmaxf(acc, 0.f);
    }
}

// ---------------- sparsity (fallback standalone) ----------------
__global__ __launch_bounds__(64) void k_sparsity(const float* __restrict__ aux, float* __restrict__ out3)
{
    int t = threadIdx.x;
    float a = aux[t] + aux[64 + t];
    float c = aux[128 + t] + aux[192 + t];
    #pragma unroll
    for (int d = 1; d < 64; d <<= 1){ a += __shfl_xor(a,d); c += __shfl_xor(c,d); }
    if (t == 0){
        const float it = 6889472.0f, jt = 237568.0f;
        float isp = 1.0f - a/it;
        float jsp = 1.0f - c/jt;
        out3[0] = isp; out3[1] = jsp;
        out3[2] = (isp*it + jsp*jt)/(it + jt);
    }
}

// ============ K4: unified + node features (grid-stride) + optional sparsity ============
#define UNQ (SZ_UNI/4)
#define NFQ (SZ_NF/4)
__global__ __launch_bounds__(256) void k_uninf(const float* __restrict__ intra_adj,
    const float* __restrict__ inter_adj, const float* __restrict__ band,
    const float* __restrict__ aux, float* __restrict__ uni, float* __restrict__ nf,
    float* __restrict__ sp, int do_sp)
{
    if (do_sp && blockIdx.x == 0 && threadIdx.x < 64){
        int t = threadIdx.x;
        float a = aux[t] + aux[64 + t];
        float c = aux[128 + t] + aux[192 + t];
        #pragma unroll
        for (int d = 1; d < 64; d <<= 1){ a += __shfl_xor(a,d); c += __shfl_xor(c,d); }
        if (t == 0){
            const float it = 6889472.0f, jt = 237568.0f;
            float isp = 1.0f - a/it;
            float jsp = 1.0f - c/jt;
            sp[0] = isp; sp[1] = jsp;
            sp[2] = (isp*it + jsp*jt)/(it + jt);
        }
    }
    int gid = blockIdx.x*256 + threadIdx.x;
    int gsz = gridDim.x*256;
    for (int q = gid; q < UNQ; q += gsz){
        int row = q / 116;
        int cq  = q - row*116;
        int b = row / KN;
        int p = row - b*KN;
        int k1 = p / NN_;
        int i  = p - k1*NN_;
        int k2 = cq / 29;
        int j0 = cq*4 - k2*NN_;
        float4 v;
        if (k2 == k1){
            v = *(const float4*)&intra_adj[(((size_t)b*NK + k1)*NN_ + i)*NN_ + j0];
        } else {
            int d = i - j0;
            float val = 0.f;
            if (d >= 0 && d < 4)
                val = inter_adj[(((size_t)b*NN_ + i)*NK + k1)*NK + k2];
            v.x = (d==0)?val:0.f;
            v.y = (d==1)?val:0.f;
            v.z = (d==2)?val:0.f;
            v.w = (d==3)?val:0.f;
        }
        *(float4*)&uni[(size_t)q*4] = v;
    }
    for (int q = gid; q < NFQ; q += gsz){
        int fq = q % 18;
        int rest = q / 18;
        int b = rest / KN;
        int p = rest - b*KN;
        int k = p / NN_;
        int n = p - k*NN_;
        float4 v = *(const float4*)&band[(((size_t)b*NN_ + n)*NK + k)*NF + fq*4];
        *(float4*)&nf[(size_t)q*4] = v;
    }
}

extern "C" void kernel_launch(void* const* d_in, const int* in_sizes, int n_in,
                              void* d_out, int out_size, void* d_ws, size_t ws_size,
                              hipStream_t stream)
{
    const float* band = (const float*)d_in[0];
    const float* attn = (const float*)d_in[1];
    const float* thA  = (const float*)d_in[2];
    const float* thE  = (const float*)d_in[3];
    const float* fw   = (const float*)d_in[4];
    const float* iW1  = (const float*)d_in[5];
    const float* ib1  = (const float*)d_in[6];
    const float* iW2  = (const float*)d_in[7];
    const float* ib2  = (const float*)d_in[8];
    const float* eW1  = (const float*)d_in[9];
    const float* eb1  = (const float*)d_in[10];
    const float* eW2  = (const float*)d_in[11];
    const float* eb2  = (const float*)d_in[12];
    const float* cW   = (const float*)d_in[13];
    const float* cb   = (const float*)d_in[14];

    float* out = (float*)d_out;
    float* uni = out + OFF_UNI;
    float* nf  = out + OFF_NF;
    float* gfo = out + OFF_GF;
    float* ia  = out + OFF_IA;
    float* ie  = out + OFF_IE;
    float* sp  = out + OFF_SP;

    float* scr_sc    = uni + SCR_SC;
    float* scr_corr  = uni + SCR_CORR;
    float* scr_dens  = uni + SCR_DENS;
    float* scr_stren = uni + SCR_STREN;

    int ws_ok = (ws_size >= 256*sizeof(float));
    float* aux = ws_ok ? (float*)d_ws : (uni + SCR_AUX);

    k_corr_inter<<<512 + BN/64, 256, 0, stream>>>(band, attn, thE, fw, eW1, eb1, eW2, eb2,
                                                  scr_corr, ie, scr_dens, scr_stren);
    k_topk_mask<<<BK, 512, 0, stream>>>(scr_corr, thA, scr_sc);
    k_mlp<<<ROWS/64, 256, 0, stream>>>(scr_sc, iW1, ib1, iW2, ib2, scr_sc);
    k_symg<<<NB, 512, 0, stream>>>(scr_sc, scr_dens, scr_stren, band, cW, cb,
                                   ia, gfo, aux);
    if (!ws_ok)
        k_sparsity<<<1, 64, 0, stream>>>(aux, sp);
    k_uninf<<<2048, 256, 0, stream>>>(ia, ie, band, aux, uni, nf, sp, ws_ok ? 1 : 0);
}

// Round 10
// 153.142 us; speedup vs baseline: 1.1810x; 1.0677x over previous
//
#include <hip/hip_runtime.h>
#include <math.h>

#define NB 128     // B
#define NN_ 116    // N
#define NK 4       // K
#define NF 72      // F
#define NS 8       // S
#define TOPK 10

#define BK (NB*NK)            // 512
#define BN (NB*NN_)           // 14848
#define NN2 (NN_*NN_)         // 13456
#define KN (NK*NN_)           // 464
#define ROWS (BK*NN_)         // 59392
#define LROW 117              // padded LDS row stride

// output section offsets (floats)
#define OFF_UNI 0
#define SZ_UNI (NB*KN*KN)                 // 27557888
#define OFF_NF (OFF_UNI + SZ_UNI)
#define SZ_NF (NB*KN*NF)                  // 4276224
#define OFF_GF (OFF_NF + SZ_NF)
#define SZ_GF (NB*128)
#define OFF_IA (OFF_GF + SZ_GF)
#define SZ_IA (NB*NK*NN_*NN_)             // 6889472
#define OFF_IE (OFF_IA + SZ_IA)
#define SZ_IE (NB*NN_*NK*NK)              // 237568
#define OFF_SP (OFF_IE + SZ_IE)

// scratch inside the unified region (consumed before k_uninf overwrites it)
#define SCR_SC 0                          // sc -> intra in-place
#define SCR_CORR (SCR_SC + SZ_IA)
#define SCR_DEG (SCR_CORR + SZ_IA)
#define SCR_CLUS (SCR_DEG + ROWS)
#define SCR_DENS (SCR_CLUS + ROWS)
#define SCR_STREN (SCR_DENS + BN)
#define SCR_AUX (SCR_STREN + BN)          // 2*NB (fallback)

#define NFQ (SZ_NF/4)        // 1069056 float4 quads
#define UNQ (SZ_UNI/4)       // 6889472 float4 quads
#define NB_CORR 512
#define NB_INTER (BN/64)     // 232
#define NB_COPY 1044

__device__ __forceinline__ float sigmoidf_(float x){ return 1.0f/(1.0f+expf(-x)); }
__device__ __forceinline__ float dot4_(float4 a, float4 b){
    return fmaf(a.x,b.x, fmaf(a.y,b.y, fmaf(a.z,b.z, a.w*b.w)));
}
#define CLIP1(x) fminf(1.0f, fmaxf(-1.0f, (x)))

// ---- FAT1: blocks [0,512)=corr; [512,744)=inter; [744,1788)=nodefeat copy ----
__global__ __launch_bounds__(256, 1) void k_corr_inter(const float* __restrict__ band,
    const float* __restrict__ attn, const float* __restrict__ thadj2,
    const float* __restrict__ fwp,
    const float* __restrict__ eW1, const float* __restrict__ eb1,
    const float* __restrict__ eW2, const float* __restrict__ eb2,
    float* __restrict__ corr_out, float* __restrict__ inter_out,
    float* __restrict__ dens_out, float* __restrict__ stren_out,
    float* __restrict__ nf)
{
    __shared__ float sx[NF*120];
    __shared__ float smu[120], srs[120];
    __shared__ float sW1[128], sb1[32], sW2[128], sb2[4];
    __shared__ float sMat[256*4];
    int t = threadIdx.x;
    if (blockIdx.x < NB_CORR){
        int bk = blockIdx.x;
        int b = bk >> 2, k = bk & 3;
        const float* xin = band + ((size_t)b*NN_*NK + k)*NF;
        for (int e = t; e < NN_*NF; e += 256){
            int n = e / NF, f = e - n*NF;
            sx[f*120 + n] = xin[(size_t)n*NK*NF + f];
        }
        for (int e = t; e < NF*4; e += 256)
            sx[(e>>2)*120 + NN_ + (e&3)] = 0.0f;
        __syncthreads();
        if (t < NN_){
            float s = 0.f, ss = 0.f;
            for (int f = 0; f < NF; ++f){ float v = sx[f*120+t]; s += v; ss += v*v; }
            float mu = s * (1.0f/NF);
            float sd = sqrtf(fmaxf(ss - s*mu, 1e-8f));
            smu[t] = mu; srs[t] = 1.0f/sd;
        }
        __syncthreads();
        for (int e = t; e < NF*NN_; e += 256){
            int f = e / NN_, n = e - f*NN_;
            sx[f*120+n] = (sx[f*120+n] - smu[n]) * srs[n];
        }
        __syncthreads();
        float* dst = corr_out + (size_t)bk * NN2;
        if (t < 225){
            int ti = t / 15, tj = t - ti*15;
            int i0 = ti*8, j0 = tj*8;
            float acc[8][8] = {};
            for (int f = 0; f < NF; ++f){
                const float4 a0 = *(const float4*)&sx[f*120 + i0];
                const float4 a1 = *(const float4*)&sx[f*120 + i0 + 4];
                const float4 c0 = *(const float4*)&sx[f*120 + j0];
                const float4 c1 = *(const float4*)&sx[f*120 + j0 + 4];
                float av[8] = {a0.x,a0.y,a0.z,a0.w,a1.x,a1.y,a1.z,a1.w};
                float cv[8] = {c0.x,c0.y,c0.z,c0.w,c1.x,c1.y,c1.z,c1.w};
                #pragma unroll
                for (int r = 0; r < 8; ++r)
                    #pragma unroll
                    for (int c = 0; c < 8; ++c)
                        acc[r][c] = fmaf(av[r], cv[c], acc[r][c]);
            }
            #pragma unroll
            for (int r = 0; r < 8; ++r){
                int i = i0 + r;
                if (i < NN_){
                    float4 v0;
                    v0.x = CLIP1(acc[r][0]); v0.y = CLIP1(acc[r][1]);
                    v0.z = CLIP1(acc[r][2]); v0.w = CLIP1(acc[r][3]);
                    *(float4*)&dst[i*NN_ + j0] = v0;
                    if (j0 + 4 <= 112){
                        float4 v1;
                        v1.x = CLIP1(acc[r][4]); v1.y = CLIP1(acc[r][5]);
                        v1.z = CLIP1(acc[r][6]); v1.w = CLIP1(acc[r][7]);
                        *(float4*)&dst[i*NN_ + j0 + 4] = v1;
                    }
                }
            }
        }
    } else if (blockIdx.x < NB_CORR + NB_INTER){
        if (t < 128) sW1[t] = eW1[t];
        if (t < 32) sb1[t] = eb1[t];
        if (t >= 128 && t < 256) sW2[t-128] = eW2[t-128];
        if (t < 4) sb2[t] = eb2[t];
        __syncthreads();
        int l = t & 3;
        int il = t >> 2;
        size_t item = (size_t)(blockIdx.x - NB_CORR)*64 + il;

        const float* xr = band + item*(NK*NF) + l*NF;
        float s=0,p0=0,p1=0,p2=0,p3=0;
        for (int f = 0; f < NF; ++f){
            float v = xr[f];
            float v1=__shfl_xor(v,1), v2=__shfl_xor(v,2), v3=__shfl_xor(v,3);
            s += v; p0=fmaf(v,v,p0); p1=fmaf(v,v1,p1); p2=fmaf(v,v2,p2); p3=fmaf(v,v3,p3);
        }
        float mu = s*(1.0f/NF);
        float mu1=__shfl_xor(mu,1), mu2=__shfl_xor(mu,2), mu3=__shfl_xor(mu,3);
        float sd = sqrtf(fmaxf(p0 - s*mu, 1e-8f));
        float sd1=__shfl_xor(sd,1), sd2=__shfl_xor(sd,2), sd3=__shfl_xor(sd,3);
        float c0 = CLIP1((p0 - (float)NF*mu*mu )/(sd*sd +1e-8f));
        float c1 = CLIP1((p1 - (float)NF*mu*mu1)/(sd*sd1+1e-8f));
        float c2 = CLIP1((p2 - (float)NF*mu*mu2)/(sd*sd2+1e-8f));
        float c3 = CLIP1((p3 - (float)NF*mu*mu3)/(sd*sd3+1e-8f));

        const float* ar = attn + item*(NS*NK) + l;
        float as=0,q0=0,q1=0,q2=0,q3=0;
        #pragma unroll
        for (int s8 = 0; s8 < NS; ++s8){
            float v = ar[s8*NK];
            float v1=__shfl_xor(v,1), v2=__shfl_xor(v,2), v3=__shfl_xor(v,3);
            as += v; q0=fmaf(v,v,q0); q1=fmaf(v,v1,q1); q2=fmaf(v,v2,q2); q3=fmaf(v,v3,q3);
        }
        float am = as*(1.0f/NS);
        float am1=__shfl_xor(am,1), am2=__shfl_xor(am,2), am3=__shfl_xor(am,3);
        float ad = sqrtf(fmaxf(q0 - as*am, 1e-8f));
        float ad1=__shfl_xor(ad,1), ad2=__shfl_xor(ad,2), ad3=__shfl_xor(ad,3);
        float a0 = CLIP1((q0 - (float)NS*am*am )/(ad*ad +1e-8f));
        float a1 = CLIP1((q1 - (float)NS*am*am1)/(ad*ad1+1e-8f));
        float a2 = CLIP1((q2 - (float)NS*am*am2)/(ad*ad2+1e-8f));
        float a3 = CLIP1((q3 - (float)NS*am*am3)/(ad*ad3+1e-8f));

        float fwv = sigmoidf_(fwp[0]);
        float g0 = fwv*c0 + (1.0f-fwv)*a0;
        float g1 = fwv*c1 + (1.0f-fwv)*a1;
        float g2 = fwv*c2 + (1.0f-fwv)*a2;
        float g3 = fwv*c3 + (1.0f-fwv)*a3;
        float th2 = 0.2f + sigmoidf_(thadj2[0])*0.2f;
        float m0 = (fabsf(g0)>th2)?g0:0.f;
        float m1 = (fabsf(g1)>th2)?g1:0.f;
        float m2 = (fabsf(g2)>th2)?g2:0.f;
        float m3 = (fabsf(g3)>th2)?g3:0.f;

        sMat[il*16 + l*4 + (l^0)] = m0;
        sMat[il*16 + l*4 + (l^1)] = m1;
        sMat[il*16 + l*4 + (l^2)] = m2;
        sMat[il*16 + l*4 + (l^3)] = m3;
        __syncthreads();
        float x0 = fmaxf(0.5f*(sMat[il*16 + l*4 + 0] + sMat[il*16 + 0*4 + l]), 0.f);
        float x1 = fmaxf(0.5f*(sMat[il*16 + l*4 + 1] + sMat[il*16 + 1*4 + l]), 0.f);
        float x2 = fmaxf(0.5f*(sMat[il*16 + l*4 + 2] + sMat[il*16 + 2*4 + l]), 0.f);
        float x3 = fmaxf(0.5f*(sMat[il*16 + l*4 + 3] + sMat[il*16 + 3*4 + l]), 0.f);

        float h[32];
        #pragma unroll
        for (int o = 0; o < 32; ++o){
            float acc = sb1[o];
            acc = fmaf(sW1[o*4+0], x0, acc);
            acc = fmaf(sW1[o*4+1], x1, acc);
            acc = fmaf(sW1[o*4+2], x2, acc);
            acc = fmaf(sW1[o*4+3], x3, acc);
            h[o] = fmaxf(acc, 0.f);
        }
        float o0=sb2[0], o1=sb2[1], o2=sb2[2], o3=sb2[3];
        #pragma unroll
        for (int o = 0; o < 32; ++o){
            float hv = h[o];
            o0 = fmaf(sW2[0*32+o], hv, o0);
            o1 = fmaf(sW2[1*32+o], hv, o1);
            o2 = fmaf(sW2[2*32+o], hv, o2);
            o3 = fmaf(sW2[3*32+o], hv, o3);
        }
        o0 = sigmoidf_(o0); o1 = sigmoidf_(o1); o2 = sigmoidf_(o2); o3 = sigmoidf_(o3);
        __syncthreads();
        sMat[il*16 + l*4 + 0] = o0;
        sMat[il*16 + l*4 + 1] = o1;
        sMat[il*16 + l*4 + 2] = o2;
        sMat[il*16 + l*4 + 3] = o3;
        __syncthreads();
        float y0 = 0.5f*(o0 + sMat[il*16 + 0*4 + l]);
        float y1 = 0.5f*(o1 + sMat[il*16 + 1*4 + l]);
        float y2 = 0.5f*(o2 + sMat[il*16 + 2*4 + l]);
        float y3 = 0.5f*(o3 + sMat[il*16 + 3*4 + l]);
        *(float4*)&inter_out[item*16 + l*4] = make_float4(y0,y1,y2,y3);

        float cnt = ((y0>0.f)?1.f:0.f) + ((y1>0.f)?1.f:0.f) + ((y2>0.f)?1.f:0.f) + ((y3>0.f)?1.f:0.f);
        float sum = y0+y1+y2+y3;
        cnt += __shfl_xor(cnt,1); cnt += __shfl_xor(cnt,2);
        sum += __shfl_xor(sum,1); sum += __shfl_xor(sum,2);
        if (l == 0){
            dens_out[item]  = cnt * (1.0f/16.0f);
            stren_out[item] = sum * (1.0f/16.0f);
        }
    } else {
        // -------- nodefeat transpose-copy (depends only on band) --------
        int gid = (blockIdx.x - NB_CORR - NB_INTER)*256 + t;
        int gsz = NB_COPY*256;
        for (int q = gid; q < NFQ; q += gsz){
            int fq = q % 18;
            int rest = q / 18;
            int b = rest / KN;
            int p = rest - b*KN;
            int k = p / NN_;
            int n = p - k*NN_;
            float4 v = *(const float4*)&band[(((size_t)b*NN_ + n)*NK + k)*NF + fq*4];
            *(float4*)&nf[(size_t)q*4] = v;
        }
    }
}

// ---------------- K1b: top-k (4 thr/row) + threshold + sym -> sc (r7) ----------------
__global__ __launch_bounds__(512) void k_topk_mask(const float* __restrict__ corr_in,
    const float* __restrict__ thadj, float* __restrict__ sc_out)
{
    __shared__ float sc_[NN_*LROW];
    __shared__ unsigned skm[NN_*4];
    __shared__ unsigned stop[464*10];
    int bk = blockIdx.x;
    int t = threadIdx.x;
    const float* src = corr_in + (size_t)bk*NN2;
    for (int e = t; e < NN2; e += 512){
        int i = e / NN_, j = e - i*NN_;
        sc_[i*LROW + j] = src[e];
    }
    __syncthreads();
    if (t < NN_*4){
        int r = t >> 2, q = t & 3;
        const float* row = &sc_[r*LROW + q*29];
        int jbase = q*29;
        unsigned tv[TOPK];
        #pragma unroll
        for (int p = 0; p < TOPK; ++p) tv[p] = 0u;
        for (int jj = 0; jj < 29; ++jj){
            float c = fabsf(row[jj]);
            unsigned u = (__float_as_uint(c) & 0xFFFFFF80u) | (unsigned)(127 - (jbase + jj));
            #pragma unroll
            for (int p = 0; p < TOPK; ++p){
                unsigned old = tv[p];
                bool gt = u > old;
                tv[p] = gt ? u : old;
                u = gt ? old : u;
            }
        }
        #pragma unroll
        for (int p = 0; p < TOPK; ++p) stop[t*10 + p] = tv[p];
    }
    __syncthreads();
    if (t < NN_){
        const unsigned* L0 = &stop[(4*t+0)*10];
        const unsigned* L1 = &stop[(4*t+1)*10];
        const unsigned* L2 = &stop[(4*t+2)*10];
        const unsigned* L3 = &stop[(4*t+3)*10];
        int i0=0, i1=0, i2=0, i3=0;
        unsigned m0=0,m1=0,m2=0,m3=0;
        #pragma unroll
        for (int p = 0; p < TOPK; ++p){
            unsigned u0 = L0[i0], u1 = L1[i1], u2 = L2[i2], u3 = L3[i3];
            unsigned ua = u0 > u1 ? u0 : u1;
            unsigned ub = u2 > u3 ? u2 : u3;
            unsigned u  = ua > ub ? ua : ub;
            if (u == u0) ++i0; else if (u == u1) ++i1; else if (u == u2) ++i2; else ++i3;
            int j = 127 - (int)(u & 127u);
            unsigned bit = 1u << (j & 31);
            int w = j >> 5;
            if (w == 0) m0 |= bit; else if (w == 1) m1 |= bit; else if (w == 2) m2 |= bit; else m3 |= bit;
        }
        skm[t*4+0]=m0; skm[t*4+1]=m1; skm[t*4+2]=m2; skm[t*4+3]=m3;
    }
    __syncthreads();
    float th = 0.1f + sigmoidf_(thadj[0]) * 0.2f;
    float* dst = sc_out + (size_t)bk * NN2;
    for (int e = t; e < NN2; e += 512){
        int i = e / NN_, j = e - i*NN_;
        float cij = sc_[i*LROW + j];
        float cji = sc_[j*LROW + i];
        bool kij = (skm[i*4 + (j>>5)] >> (j&31)) & 1u;
        bool kji = (skm[j*4 + (i>>5)] >> (i&31)) & 1u;
        float mij = (fabsf(cij) > th && kij) ? cij : 0.0f;
        float mji = (fabsf(cji) > th && kji) ? cji : 0.0f;
        dst[e] = fmaxf(0.5f*(mij+mji), 0.0f);
    }
}

// ---------------- K2: fused MLP (H in LDS), 64 rows/block (r6) ----------------
__global__ __launch_bounds__(256) void k_mlp(const float* __restrict__ sc,
    const float* __restrict__ W1, const float* __restrict__ b1,
    const float* __restrict__ W2, const float* __restrict__ b2,
    float* __restrict__ intra)
{
    __shared__ float sA_[14848];
    __shared__ float sH[64*68];
    __shared__ float sb1[64];
    __shared__ float sb2[128];
    int t = threadIdx.x;
    int r0 = blockIdx.x * 64;
    float* srow = sA_;
    float* sW1  = sA_ + 7424;
    for (int e4 = t; e4 < 1856; e4 += 256){
        *(float4*)&srow[e4*4] = *(const float4*)&sc[(size_t)r0*116 + e4*4];
        *(float4*)&sW1[e4*4]  = *(const float4*)&W1[e4*4];
    }
    if (t < 64) sb1[t] = b1[t];
    if (t < 128) sb2[t] = (t < NN_) ? b2[t] : 0.0f;
    __syncthreads();
    {
        int rg = t >> 4, og = t & 15;
        float acc[4][4] = {};
        for (int j4 = 0; j4 < 29; ++j4){
            float4 s[4], w[4];
            #pragma unroll
            for (int m = 0; m < 4; ++m) s[m] = *(const float4*)&srow[(rg+16*m)*116 + j4*4];
            #pragma unroll
            for (int n = 0; n < 4; ++n) w[n] = *(const float4*)&sW1[(og+16*n)*116 + j4*4];
            #pragma unroll
            for (int m = 0; m < 4; ++m)
                #pragma unroll
                for (int n = 0; n < 4; ++n)
                    acc[m][n] += dot4_(s[m], w[n]);
        }
        #pragma unroll
        for (int m = 0; m < 4; ++m)
            #pragma unroll
            for (int n = 0; n < 4; ++n)
                sH[(rg+16*m)*68 + og+16*n] = fmaxf(acc[m][n] + sb1[og+16*n], 0.0f);
    }
    __syncthreads();
    float* sW2 = sA_;
    for (int e = t; e < 128*64; e += 256){
        int j = e >> 6, o = e & 63;
        sW2[j*76 + o] = (j < NN_) ? W2[e] : 0.0f;
    }
    __syncthreads();
    {
        int rg = t >> 4, jg = t & 15;
        float acc[4][8] = {};
        for (int o4 = 0; o4 < 16; ++o4){
            float4 h[4], w[8];
            #pragma unroll
            for (int m = 0; m < 4; ++m) h[m] = *(const float4*)&sH[(rg+16*m)*68 + o4*4];
            #pragma unroll
            for (int q = 0; q < 8; ++q) w[q] = *(const float4*)&sW2[(jg+16*q)*76 + o4*4];
            #pragma unroll
            for (int m = 0; m < 4; ++m)
                #pragma unroll
                for (int q = 0; q < 8; ++q)
                    acc[m][q] += dot4_(h[m], w[q]);
        }
        #pragma unroll
        for (int m = 0; m < 4; ++m){
            int row = r0 + rg + 16*m;
            #pragma unroll
            for (int q = 0; q < 8; ++q){
                int j = jg + 16*q;
                if (j < NN_)
                    intra[(size_t)row*116 + j] = sigmoidf_(acc[m][q] + sb2[j]);
            }
        }
    }
}

// ---------------- K3: sym + deg/clus (r7: 512 blocks, 512 thr) ----------------
__global__ __launch_bounds__(512) void k_sym_intra(const float* __restrict__ intra,
    float* __restrict__ intra_adj, float* __restrict__ deg_out, float* __restrict__ clus_out)
{
    __shared__ float sm[NN_*LROW];
    int bk = blockIdx.x, t = threadIdx.x;
    const float* src = intra + (size_t)bk*NN2;
    for (int e = t; e < NN2; e += 512){
        int i = e / NN_, j = e - i*NN_;
        sm[i*LROW + j] = src[e];
    }
    __syncthreads();
    float* dst = intra_adj + (size_t)bk*NN2;
    for (int e = t; e < NN2; e += 512){
        int i = e / NN_, j = e - i*NN_;
        dst[e] = 0.5f*(sm[i*LROW + j] + sm[j*LROW + i]);
    }
    if (t < NN_*4){
        int r = t >> 2, q = t & 3;
        float tri = 0.f, dg = 0.f;
        for (int jj = 0; jj < 29; ++jj){
            int j = q*29 + jj;
            float v = 0.5f*(sm[r*LROW+j] + sm[j*LROW+r]);
            tri = fmaf(v, v, tri);
            dg += (v > 0.f) ? 1.f : 0.f;
        }
        tri += __shfl_xor(tri,1); tri += __shfl_xor(tri,2);
        dg  += __shfl_xor(dg,1);  dg  += __shfl_xor(dg,2);
        if (q == 0){
            deg_out[(size_t)bk*NN_ + r]  = dg;
            clus_out[(size_t)bk*NN_ + r] = tri / (dg*dg + 1e-8f);
        }
    }
}

// ---------------- graph stats (incl. band mean/std) + graph linear (r7) ----------------
__global__ __launch_bounds__(256) void k_gstats_lin(const float* __restrict__ band,
    const float* __restrict__ deg, const float* __restrict__ clus,
    const float* __restrict__ dens, const float* __restrict__ stren,
    const float* __restrict__ Wc, const float* __restrict__ bc,
    float* __restrict__ gfo, float* __restrict__ aux)
{
    int b = blockIdx.x, t = threadIdx.x;
    __shared__ float sGf[152];
    __shared__ float sPs[18*14*4];
    __shared__ float sPq[18*14*4];
    __shared__ float sA[4], sB[4];

    if (t < 252){
        int fq = t % 18, g = t / 18;
        float4 s = make_float4(0,0,0,0), q = make_float4(0,0,0,0);
        const float* base = band + (size_t)b*(KN*NF);
        for (int nk = g; nk < KN; nk += 14){
            float4 v = *(const float4*)&base[nk*NF + fq*4];
            s.x += v.x; s.y += v.y; s.z += v.z; s.w += v.w;
            q.x = fmaf(v.x,v.x,q.x); q.y = fmaf(v.y,v.y,q.y);
            q.z = fmaf(v.z,v.z,q.z); q.w = fmaf(v.w,v.w,q.w);
        }
        int idx = (fq*14 + g)*4;
        *(float4*)&sPs[idx] = s;
        *(float4*)&sPq[idx] = q;
    }
    __syncthreads();
    if (t < NF){
        int fq = t >> 2, e = t & 3;
        float S = 0.f, Q = 0.f;
        for (int g = 0; g < 14; ++g){ S += sPs[(fq*14+g)*4+e]; Q += sPq[(fq*14+g)*4+e]; }
        float mean = S * (1.0f/(float)KN);
        float var = fmaxf((Q - S*mean)/((float)KN - 1.0f), 0.0f);
        sGf[t] = mean;
        sGf[NF + t] = sqrtf(var);
    }
    __syncthreads();

    float s = 0.f, ss = 0.f;
    for (int e = t; e < KN; e += 256){ float v = deg[(size_t)b*KN + e]; s += v; ss += v*v; }
    #pragma unroll
    for (int d = 1; d < 64; d <<= 1){ s += __shfl_xor(s,d); ss += __shfl_xor(ss,d); }
    if ((t & 63) == 0){ sA[t>>6] = s; sB[t>>6] = ss; }
    __syncthreads();
    if (t == 0){
        float S0 = sA[0]+sA[1]+sA[2]+sA[3], S1 = sB[0]+sB[1]+sB[2]+sB[3];
        float Mv = (float)KN, mean = S0/Mv;
        float var = fmaxf((S1 - S0*mean)/(Mv - 1.0f), 0.0f);
        sGf[144] = mean; sGf[145] = sqrtf(var);
        aux[b] = S0;
    }
    __syncthreads();

    s = 0.f; ss = 0.f;
    for (int e = t; e < KN; e += 256){ float v = clus[(size_t)b*KN + e]; s += v; ss += v*v; }
    #pragma unroll
    for (int d = 1; d < 64; d <<= 1){ s += __shfl_xor(s,d); ss += __shfl_xor(ss,d); }
    if ((t & 63) == 0){ sA[t>>6] = s; sB[t>>6] = ss; }
    __syncthreads();
    if (t == 0){
        float S0 = sA[0]+sA[1]+sA[2]+sA[3], S1 = sB[0]+sB[1]+sB[2]+sB[3];
        float Mv = (float)KN, mean = S0/Mv;
        float var = fmaxf((S1 - S0*mean)/(Mv - 1.0f), 0.0f);
        sGf[146] = mean; sGf[147] = sqrtf(var);
    }
    __syncthreads();

    s = 0.f; ss = 0.f;
    for (int e = t; e < NN_; e += 256){ s += dens[(size_t)b*NN_ + e]; ss += stren[(size_t)b*NN_ + e]; }
    #pragma unroll
    for (int d = 1; d < 64; d <<= 1){ s += __shfl_xor(s,d); ss += __shfl_xor(ss,d); }
    if ((t & 63) == 0){ sA[t>>6] = s; sB[t>>6] = ss; }
    __syncthreads();
    if (t == 0){
        float S0 = sA[0]+sA[1]+sA[2]+sA[3], S1 = sB[0]+sB[1]+sB[2]+sB[3];
        sGf[148] = S0 / (float)NN_;
        sGf[149] = S1 / (float)NN_;
        aux[128 + b] = S0 * 16.0f;
    }
    __syncthreads();

    if (t < 128){
        float acc = bc[t];
        const float* w = Wc + (size_t)t*150;
        for (int c = 0; c < 150; ++c) acc = fmaf(sGf[c], w[c], acc);
        gfo[(size_t)b*128 + t] = fmaxf(acc, 0.f);
    }
}

// ---------------- sparsity (fallback standalone) ----------------
__global__ __launch_bounds__(64) void k_sparsity(const float* __restrict__ aux, float* __restrict__ out3)
{
    int t = threadIdx.x;
    float a = aux[t] + aux[64 + t];
    float c = aux[128 + t] + aux[192 + t];
    #pragma unroll
    for (int d = 1; d < 64; d <<= 1){ a += __shfl_xor(a,d); c += __shfl_xor(c,d); }
    if (t == 0){
        const float it = 6889472.0f, jt = 237568.0f;
        float isp = 1.0f - a/it;
        float jsp = 1.0f - c/jt;
        out3[0] = isp; out3[1] = jsp;
        out3[2] = (isp*it + jsp*jt)/(it + jt);
    }
}

// ============ K4: unified assembly (grid-stride) + optional sparsity ============
__global__ __launch_bounds__(256) void k_uninf(const float* __restrict__ intra_adj,
    const float* __restrict__ inter_adj, const float* __restrict__ aux,
    float* __restrict__ uni, float* __restrict__ sp, int do_sp)
{
    if (do_sp && blockIdx.x == 0 && threadIdx.x < 64){
        int t = threadIdx.x;
        float a = aux[t] + aux[64 + t];
        float c = aux[128 + t] + aux[192 + t];
        #pragma unroll
        for (int d = 1; d < 64; d <<= 1){ a += __shfl_xor(a,d); c += __shfl_xor(c,d); }
        if (t == 0){
            const float it = 6889472.0f, jt = 237568.0f;
            float isp = 1.0f - a/it;
            float jsp = 1.0f - c/jt;
            sp[0] = isp; sp[1] = jsp;
            sp[2] = (isp*it + jsp*jt)/(it + jt);
        }
    }
    int gid = blockIdx.x*256 + threadIdx.x;
    int gsz = gridDim.x*256;
    for (int q = gid; q < UNQ; q += gsz){
        int row = q / 116;
        int cq  = q - row*116;
        int b = row / KN;
        int p = row - b*KN;
        int k1 = p / NN_;
        int i  = p - k1*NN_;
        int k2 = cq / 29;
        int j0 = cq*4 - k2*NN_;
        float4 v;
        if (k2 == k1){
            v = *(const float4*)&intra_adj[(((size_t)b*NK + k1)*NN_ + i)*NN_ + j0];
        } else {
            int d = i - j0;
            float val = 0.f;
            if (d >= 0 && d < 4)
                val = inter_adj[(((size_t)b*NN_ + i)*NK + k1)*NK + k2];
            v.x = (d==0)?val:0.f;
            v.y = (d==1)?val:0.f;
            v.z = (d==2)?val:0.f;
            v.w = (d==3)?val:0.f;
        }
        *(float4*)&uni[(size_t)q*4] = v;
    }
}

extern "C" void kernel_launch(void* const* d_in, const int* in_sizes, int n_in,
                              void* d_out, int out_size, void* d_ws, size_t ws_size,
                              hipStream_t stream)
{
    const float* band = (const float*)d_in[0];
    const float* attn = (const float*)d_in[1];
    const float* thA  = (const float*)d_in[2];
    const float* thE  = (const float*)d_in[3];
    const float* fw   = (const float*)d_in[4];
    const float* iW1  = (const float*)d_in[5];
    const float* ib1  = (const float*)d_in[6];
    const float* iW2  = (const float*)d_in[7];
    const float* ib2  = (const float*)d_in[8];
    const float* eW1  = (const float*)d_in[9];
    const float* eb1  = (const float*)d_in[10];
    const float* eW2  = (const float*)d_in[11];
    const float* eb2  = (const float*)d_in[12];
    const float* cW   = (const float*)d_in[13];
    const float* cb   = (const float*)d_in[14];

    float* out = (float*)d_out;
    float* uni = out + OFF_UNI;
    float* nf  = out + OFF_NF;
    float* gfo = out + OFF_GF;
    float* ia  = out + OFF_IA;
    float* ie  = out + OFF_IE;
    float* sp  = out + OFF_SP;

    float* scr_sc    = uni + SCR_SC;
    float* scr_corr  = uni + SCR_CORR;
    float* scr_deg   = uni + SCR_DEG;
    float* scr_clus  = uni + SCR_CLUS;
    float* scr_dens  = uni + SCR_DENS;
    float* scr_stren = uni + SCR_STREN;

    int ws_ok = (ws_size >= 256*sizeof(float));
    float* aux = ws_ok ? (float*)d_ws : (uni + SCR_AUX);

    k_corr_inter<<<NB_CORR + NB_INTER + NB_COPY, 256, 0, stream>>>(
        band, attn, thE, fw, eW1, eb1, eW2, eb2,
        scr_corr, ie, scr_dens, scr_stren, nf);
    k_topk_mask<<<BK, 512, 0, stream>>>(scr_corr, thA, scr_sc);
    k_mlp<<<ROWS/64, 256, 0, stream>>>(scr_sc, iW1, ib1, iW2, ib2, scr_sc);
    k_sym_intra<<<BK, 512, 0, stream>>>(scr_sc, ia, scr_deg, scr_clus);
    k_gstats_lin<<<NB, 256, 0, stream>>>(band, scr_deg, scr_clus, scr_dens, scr_stren,
                                         cW, cb, gfo, aux);
    if (!ws_ok)
        k_sparsity<<<1, 64, 0, stream>>>(aux, sp);
    k_uninf<<<2048, 256, 0, stream>>>(ia, ie, aux, uni, sp, ws_ok ? 1 : 0);
}

// Round 11
// 149.680 us; speedup vs baseline: 1.2083x; 1.0231x over previous
//
#include <hip/hip_runtime.h>
#include <math.h>

#define NB 128     // B
#define NN_ 116    // N
#define NK 4       // K
#define NF 72      // F
#define NS 8       // S
#define TOPK 10

#define BK (NB*NK)            // 512
#define BN (NB*NN_)           // 14848
#define NN2 (NN_*NN_)         // 13456
#define KN (NK*NN_)           // 464
#define ROWS (BK*NN_)         // 59392
#define LROW 117              // padded LDS row stride

// output section offsets (floats)
#define OFF_UNI 0
#define SZ_UNI (NB*KN*KN)                 // 27557888
#define OFF_NF (OFF_UNI + SZ_UNI)
#define SZ_NF (NB*KN*NF)                  // 4276224
#define OFF_GF (OFF_NF + SZ_NF)
#define SZ_GF (NB*128)
#define OFF_IA (OFF_GF + SZ_GF)
#define SZ_IA (NB*NK*NN_*NN_)             // 6889472
#define OFF_IE (OFF_IA + SZ_IA)
#define SZ_IE (NB*NN_*NK*NK)              // 237568
#define OFF_SP (OFF_IE + SZ_IE)

// scratch inside the unified region (consumed before k_uninf overwrites it)
#define SCR_SC 0                          // sc (SZ_IA floats)
#define SCR_CORR (SCR_SC + SZ_IA)
#define SCR_DEG (SCR_CORR + SZ_IA)
#define SCR_CLUS (SCR_DEG + ROWS)
#define SCR_DENS (SCR_CLUS + ROWS)
#define SCR_STREN (SCR_DENS + BN)
#define SCR_AUX (SCR_STREN + BN)          // 2*NB (fallback)

#define NFQ (SZ_NF/4)        // 1069056 float4 quads
#define UNQ (SZ_UNI/4)       // 6889472 float4 quads
#define NB_CORR 512
#define NB_INTER (BN/64)     // 232
#define NB_COPY 1044

__device__ __forceinline__ float sigmoidf_(float x){ return 1.0f/(1.0f+expf(-x)); }
__device__ __forceinline__ float dot4_(float4 a, float4 b){
    return fmaf(a.x,b.x, fmaf(a.y,b.y, fmaf(a.z,b.z, a.w*b.w)));
}
#define CLIP1(x) fminf(1.0f, fmaxf(-1.0f, (x)))

// ---- FAT1: blocks [0,512)=corr; [512,744)=inter; [744,1788)=nodefeat copy ----
__global__ __launch_bounds__(256, 1) void k_corr_inter(const float* __restrict__ band,
    const float* __restrict__ attn, const float* __restrict__ thadj2,
    const float* __restrict__ fwp,
    const float* __restrict__ eW1, const float* __restrict__ eb1,
    const float* __restrict__ eW2, const float* __restrict__ eb2,
    float* __restrict__ corr_out, float* __restrict__ inter_out,
    float* __restrict__ dens_out, float* __restrict__ stren_out,
    float* __restrict__ nf)
{
    __shared__ float sx[NF*120];
    __shared__ float smu[120], srs[120];
    __shared__ float sW1[128], sb1[32], sW2[128], sb2[4];
    __shared__ float sMat[256*4];
    int t = threadIdx.x;
    if (blockIdx.x < NB_CORR){
        int bk = blockIdx.x;
        int b = bk >> 2, k = bk & 3;
        const float* xin = band + ((size_t)b*NN_*NK + k)*NF;
        for (int e = t; e < NN_*NF; e += 256){
            int n = e / NF, f = e - n*NF;
            sx[f*120 + n] = xin[(size_t)n*NK*NF + f];
        }
        for (int e = t; e < NF*4; e += 256)
            sx[(e>>2)*120 + NN_ + (e&3)] = 0.0f;
        __syncthreads();
        if (t < NN_){
            float s = 0.f, ss = 0.f;
            for (int f = 0; f < NF; ++f){ float v = sx[f*120+t]; s += v; ss += v*v; }
            float mu = s * (1.0f/NF);
            float sd = sqrtf(fmaxf(ss - s*mu, 1e-8f));
            smu[t] = mu; srs[t] = 1.0f/sd;
        }
        __syncthreads();
        for (int e = t; e < NF*NN_; e += 256){
            int f = e / NN_, n = e - f*NN_;
            sx[f*120+n] = (sx[f*120+n] - smu[n]) * srs[n];
        }
        __syncthreads();
        float* dst = corr_out + (size_t)bk * NN2;
        if (t < 225){
            int ti = t / 15, tj = t - ti*15;
            int i0 = ti*8, j0 = tj*8;
            float acc[8][8] = {};
            for (int f = 0; f < NF; ++f){
                const float4 a0 = *(const float4*)&sx[f*120 + i0];
                const float4 a1 = *(const float4*)&sx[f*120 + i0 + 4];
                const float4 c0 = *(const float4*)&sx[f*120 + j0];
                const float4 c1 = *(const float4*)&sx[f*120 + j0 + 4];
                float av[8] = {a0.x,a0.y,a0.z,a0.w,a1.x,a1.y,a1.z,a1.w};
                float cv[8] = {c0.x,c0.y,c0.z,c0.w,c1.x,c1.y,c1.z,c1.w};
                #pragma unroll
                for (int r = 0; r < 8; ++r)
                    #pragma unroll
                    for (int c = 0; c < 8; ++c)
                        acc[r][c] = fmaf(av[r], cv[c], acc[r][c]);
            }
            #pragma unroll
            for (int r = 0; r < 8; ++r){
                int i = i0 + r;
                if (i < NN_){
                    float4 v0;
                    v0.x = CLIP1(acc[r][0]); v0.y = CLIP1(acc[r][1]);
                    v0.z = CLIP1(acc[r][2]); v0.w = CLIP1(acc[r][3]);
                    *(float4*)&dst[i*NN_ + j0] = v0;
                    if (j0 + 4 <= 112){
                        float4 v1;
                        v1.x = CLIP1(acc[r][4]); v1.y = CLIP1(acc[r][5]);
                        v1.z = CLIP1(acc[r][6]); v1.w = CLIP1(acc[r][7]);
                        *(float4*)&dst[i*NN_ + j0 + 4] = v1;
                    }
                }
            }
        }
    } else if (blockIdx.x < NB_CORR + NB_INTER){
        if (t < 128) sW1[t] = eW1[t];
        if (t < 32) sb1[t] = eb1[t];
        if (t >= 128 && t < 256) sW2[t-128] = eW2[t-128];
        if (t < 4) sb2[t] = eb2[t];
        __syncthreads();
        int l = t & 3;
        int il = t >> 2;
        size_t item = (size_t)(blockIdx.x - NB_CORR)*64 + il;

        const float* xr = band + item*(NK*NF) + l*NF;
        float s=0,p0=0,p1=0,p2=0,p3=0;
        for (int f = 0; f < NF; ++f){
            float v = xr[f];
            float v1=__shfl_xor(v,1), v2=__shfl_xor(v,2), v3=__shfl_xor(v,3);
            s += v; p0=fmaf(v,v,p0); p1=fmaf(v,v1,p1); p2=fmaf(v,v2,p2); p3=fmaf(v,v3,p3);
        }
        float mu = s*(1.0f/NF);
        float mu1=__shfl_xor(mu,1), mu2=__shfl_xor(mu,2), mu3=__shfl_xor(mu,3);
        float sd = sqrtf(fmaxf(p0 - s*mu, 1e-8f));
        float sd1=__shfl_xor(sd,1), sd2=__shfl_xor(sd,2), sd3=__shfl_xor(sd,3);
        float c0 = CLIP1((p0 - (float)NF*mu*mu )/(sd*sd +1e-8f));
        float c1 = CLIP1((p1 - (float)NF*mu*mu1)/(sd*sd1+1e-8f));
        float c2 = CLIP1((p2 - (float)NF*mu*mu2)/(sd*sd2+1e-8f));
        float c3 = CLIP1((p3 - (float)NF*mu*mu3)/(sd*sd3+1e-8f));

        const float* ar = attn + item*(NS*NK) + l;
        float as=0,q0=0,q1=0,q2=0,q3=0;
        #pragma unroll
        for (int s8 = 0; s8 < NS; ++s8){
            float v = ar[s8*NK];
            float v1=__shfl_xor(v,1), v2=__shfl_xor(v,2), v3=__shfl_xor(v,3);
            as += v; q0=fmaf(v,v,q0); q1=fmaf(v,v1,q1); q2=fmaf(v,v2,q2); q3=fmaf(v,v3,q3);
        }
        float am = as*(1.0f/NS);
        float am1=__shfl_xor(am,1), am2=__shfl_xor(am,2), am3=__shfl_xor(am,3);
        float ad = sqrtf(fmaxf(q0 - as*am, 1e-8f));
        float ad1=__shfl_xor(ad,1), ad2=__shfl_xor(ad,2), ad3=__shfl_xor(ad,3);
        float a0 = CLIP1((q0 - (float)NS*am*am )/(ad*ad +1e-8f));
        float a1 = CLIP1((q1 - (float)NS*am*am1)/(ad*ad1+1e-8f));
        float a2 = CLIP1((q2 - (float)NS*am*am2)/(ad*ad2+1e-8f));
        float a3 = CLIP1((q3 - (float)NS*am*am3)/(ad*ad3+1e-8f));

        float fwv = sigmoidf_(fwp[0]);
        float g0 = fwv*c0 + (1.0f-fwv)*a0;
        float g1 = fwv*c1 + (1.0f-fwv)*a1;
        float g2 = fwv*c2 + (1.0f-fwv)*a2;
        float g3 = fwv*c3 + (1.0f-fwv)*a3;
        float th2 = 0.2f + sigmoidf_(thadj2[0])*0.2f;
        float m0 = (fabsf(g0)>th2)?g0:0.f;
        float m1 = (fabsf(g1)>th2)?g1:0.f;
        float m2 = (fabsf(g2)>th2)?g2:0.f;
        float m3 = (fabsf(g3)>th2)?g3:0.f;

        sMat[il*16 + l*4 + (l^0)] = m0;
        sMat[il*16 + l*4 + (l^1)] = m1;
        sMat[il*16 + l*4 + (l^2)] = m2;
        sMat[il*16 + l*4 + (l^3)] = m3;
        __syncthreads();
        float x0 = fmaxf(0.5f*(sMat[il*16 + l*4 + 0] + sMat[il*16 + 0*4 + l]), 0.f);
        float x1 = fmaxf(0.5f*(sMat[il*16 + l*4 + 1] + sMat[il*16 + 1*4 + l]), 0.f);
        float x2 = fmaxf(0.5f*(sMat[il*16 + l*4 + 2] + sMat[il*16 + 2*4 + l]), 0.f);
        float x3 = fmaxf(0.5f*(sMat[il*16 + l*4 + 3] + sMat[il*16 + 3*4 + l]), 0.f);

        float h[32];
        #pragma unroll
        for (int o = 0; o < 32; ++o){
            float acc = sb1[o];
            acc = fmaf(sW1[o*4+0], x0, acc);
            acc = fmaf(sW1[o*4+1], x1, acc);
            acc = fmaf(sW1[o*4+2], x2, acc);
            acc = fmaf(sW1[o*4+3], x3, acc);
            h[o] = fmaxf(acc, 0.f);
        }
        float o0=sb2[0], o1=sb2[1], o2=sb2[2], o3=sb2[3];
        #pragma unroll
        for (int o = 0; o < 32; ++o){
            float hv = h[o];
            o0 = fmaf(sW2[0*32+o], hv, o0);
            o1 = fmaf(sW2[1*32+o], hv, o1);
            o2 = fmaf(sW2[2*32+o], hv, o2);
            o3 = fmaf(sW2[3*32+o], hv, o3);
        }
        o0 = sigmoidf_(o0); o1 = sigmoidf_(o1); o2 = sigmoidf_(o2); o3 = sigmoidf_(o3);
        __syncthreads();
        sMat[il*16 + l*4 + 0] = o0;
        sMat[il*16 + l*4 + 1] = o1;
        sMat[il*16 + l*4 + 2] = o2;
        sMat[il*16 + l*4 + 3] = o3;
        __syncthreads();
        float y0 = 0.5f*(o0 + sMat[il*16 + 0*4 + l]);
        float y1 = 0.5f*(o1 + sMat[il*16 + 1*4 + l]);
        float y2 = 0.5f*(o2 + sMat[il*16 + 2*4 + l]);
        float y3 = 0.5f*(o3 + sMat[il*16 + 3*4 + l]);
        *(float4*)&inter_out[item*16 + l*4] = make_float4(y0,y1,y2,y3);

        float cnt = ((y0>0.f)?1.f:0.f) + ((y1>0.f)?1.f:0.f) + ((y2>0.f)?1.f:0.f) + ((y3>0.f)?1.f:0.f);
        float sum = y0+y1+y2+y3;
        cnt += __shfl_xor(cnt,1); cnt += __shfl_xor(cnt,2);
        sum += __shfl_xor(sum,1); sum += __shfl_xor(sum,2);
        if (l == 0){
            dens_out[item]  = cnt * (1.0f/16.0f);
            stren_out[item] = sum * (1.0f/16.0f);
        }
    } else {
        int gid = (blockIdx.x - NB_CORR - NB_INTER)*256 + t;
        int gsz = NB_COPY*256;
        for (int q = gid; q < NFQ; q += gsz){
            int fq = q % 18;
            int rest = q / 18;
            int b = rest / KN;
            int p = rest - b*KN;
            int k = p / NN_;
            int n = p - k*NN_;
            float4 v = *(const float4*)&band[(((size_t)b*NN_ + n)*NK + k)*NF + fq*4];
            *(float4*)&nf[(size_t)q*4] = v;
        }
    }
}

// ---------------- K1b: top-k (4 thr/row) + threshold + sym -> sc (r7) ----------------
__global__ __launch_bounds__(512) void k_topk_mask(const float* __restrict__ corr_in,
    const float* __restrict__ thadj, float* __restrict__ sc_out)
{
    __shared__ float sc_[NN_*LROW];
    __shared__ unsigned skm[NN_*4];
    __shared__ unsigned stop[464*10];
    int bk = blockIdx.x;
    int t = threadIdx.x;
    const float* src = corr_in + (size_t)bk*NN2;
    for (int e = t; e < NN2; e += 512){
        int i = e / NN_, j = e - i*NN_;
        sc_[i*LROW + j] = src[e];
    }
    __syncthreads();
    if (t < NN_*4){
        int r = t >> 2, q = t & 3;
        const float* row = &sc_[r*LROW + q*29];
        int jbase = q*29;
        unsigned tv[TOPK];
        #pragma unroll
        for (int p = 0; p < TOPK; ++p) tv[p] = 0u;
        for (int jj = 0; jj < 29; ++jj){
            float c = fabsf(row[jj]);
            unsigned u = (__float_as_uint(c) & 0xFFFFFF80u) | (unsigned)(127 - (jbase + jj));
            #pragma unroll
            for (int p = 0; p < TOPK; ++p){
                unsigned old = tv[p];
                bool gt = u > old;
                tv[p] = gt ? u : old;
                u = gt ? old : u;
            }
        }
        #pragma unroll
        for (int p = 0; p < TOPK; ++p) stop[t*10 + p] = tv[p];
    }
    __syncthreads();
    if (t < NN_){
        const unsigned* L0 = &stop[(4*t+0)*10];
        const unsigned* L1 = &stop[(4*t+1)*10];
        const unsigned* L2 = &stop[(4*t+2)*10];
        const unsigned* L3 = &stop[(4*t+3)*10];
        int i0=0, i1=0, i2=0, i3=0;
        unsigned m0=0,m1=0,m2=0,m3=0;
        #pragma unroll
        for (int p = 0; p < TOPK; ++p){
            unsigned u0 = L0[i0], u1 = L1[i1], u2 = L2[i2], u3 = L3[i3];
            unsigned ua = u0 > u1 ? u0 : u1;
            unsigned ub = u2 > u3 ? u2 : u3;
            unsigned u  = ua > ub ? ua : ub;
            if (u == u0) ++i0; else if (u == u1) ++i1; else if (u == u2) ++i2; else ++i3;
            int j = 127 - (int)(u & 127u);
            unsigned bit = 1u << (j & 31);
            int w = j >> 5;
            if (w == 0) m0 |= bit; else if (w == 1) m1 |= bit; else if (w == 2) m2 |= bit; else m3 |= bit;
        }
        skm[t*4+0]=m0; skm[t*4+1]=m1; skm[t*4+2]=m2; skm[t*4+3]=m3;
    }
    __syncthreads();
    float th = 0.1f + sigmoidf_(thadj[0]) * 0.2f;
    float* dst = sc_out + (size_t)bk * NN2;
    for (int e = t; e < NN2; e += 512){
        int i = e / NN_, j = e - i*NN_;
        float cij = sc_[i*LROW + j];
        float cji = sc_[j*LROW + i];
        bool kij = (skm[i*4 + (j>>5)] >> (j&31)) & 1u;
        bool kji = (skm[j*4 + (i>>5)] >> (i&31)) & 1u;
        float mij = (fabsf(cij) > th && kij) ? cij : 0.0f;
        float mji = (fabsf(cji) > th && kji) ? cji : 0.0f;
        dst[e] = fmaxf(0.5f*(mij+mji), 0.0f);
    }
}

// ============ K2: fused MLP + sym + deg/clus, one block per (b,k) ============
// LDS (floats): A=14036 (sc[116][116] -> intra[116][121]); B=9728 (W1[64][116] -> W2[128][76]);
// H=7888 ([116][68]); sb1=64; sb2=128. Total 31844 floats = 127.4 KB -> 1 block/CU, 8 waves.
// All phases parallel-dense (no serial scans) so 1 block/CU is safe; per-thread
// arrays identical to the r6-proven k_mlp (acc[4][4] / acc[4][8]).
__global__ __launch_bounds__(512) void k_mlpsym(const float* __restrict__ sc,
    const float* __restrict__ W1, const float* __restrict__ b1,
    const float* __restrict__ W2, const float* __restrict__ b2,
    float* __restrict__ ia, float* __restrict__ deg_out, float* __restrict__ clus_out)
{
    __shared__ float smem[31844];
    float* sA  = smem;             // sc[116][116] then intra[116][121]
    float* sB  = smem + 14036;     // W1 then W2
    float* sH  = smem + 23764;     // [116][68]
    float* sb1 = smem + 31652;
    float* sb2 = smem + 31716;
    int bk = blockIdx.x, t = threadIdx.x;

    const float* src = sc + (size_t)bk*NN2;
    for (int e4 = t; e4 < NN2/4; e4 += 512)
        *(float4*)&sA[e4*4] = *(const float4*)&src[e4*4];
    for (int e4 = t; e4 < 1856; e4 += 512)
        *(float4*)&sB[e4*4] = *(const float4*)&W1[e4*4];
    if (t < 64) sb1[t] = b1[t];
    if (t >= 64 && t < 192) sb2[t-64] = (t-64 < NN_) ? b2[t-64] : 0.0f;
    __syncthreads();

    // phase1: H[116][64] = relu(sc @ W1^T + b1); rows rg+29m, outs og+16n
    if (t < 464){
        int rg = t >> 4, og = t & 15;
        float acc[4][4] = {};
        for (int j4 = 0; j4 < 29; ++j4){
            float4 s[4], w[4];
            #pragma unroll
            for (int m = 0; m < 4; ++m) s[m] = *(const float4*)&sA[(rg+29*m)*116 + j4*4];
            #pragma unroll
            for (int n = 0; n < 4; ++n) w[n] = *(const float4*)&sB[(og+16*n)*116 + j4*4];
            #pragma unroll
            for (int m = 0; m < 4; ++m)
                #pragma unroll
                for (int n = 0; n < 4; ++n)
                    acc[m][n] += dot4_(s[m], w[n]);
        }
        #pragma unroll
        for (int m = 0; m < 4; ++m)
            #pragma unroll
            for (int n = 0; n < 4; ++n)
                sH[(rg+29*m)*68 + og+16*n] = fmaxf(acc[m][n] + sb1[og+16*n], 0.0f);
    }
    __syncthreads();

    // load W2 -> sB [128][76] (zero-padded rows >= 116)
    for (int e = t; e < 128*64; e += 512){
        int j = e >> 6, o = e & 63;
        sB[j*76 + o] = (j < NN_) ? W2[e] : 0.0f;
    }
    __syncthreads();

    // phase2: intra = sigmoid(H @ W2^T + b2) -> sA at stride 121
    if (t < 464){
        int rg = t >> 4, jg = t & 15;
        float acc[4][8] = {};
        for (int o4 = 0; o4 < 16; ++o4){
            float4 h[4], w[8];
            #pragma unroll
            for (int m = 0; m < 4; ++m) h[m] = *(const float4*)&sH[(rg+29*m)*68 + o4*4];
            #pragma unroll
            for (int q = 0; q < 8; ++q) w[q] = *(const float4*)&sB[(jg+16*q)*76 + o4*4];
            #pragma unroll
            for (int m = 0; m < 4; ++m)
                #pragma unroll
                for (int q = 0; q < 8; ++q)
                    acc[m][q] += dot4_(h[m], w[q]);
        }
        #pragma unroll
        for (int m = 0; m < 4; ++m){
            int row = rg + 29*m;
            #pragma unroll
            for (int q = 0; q < 8; ++q){
                int j = jg + 16*q;
                if (j < NN_)
                    sA[row*121 + j] = sigmoidf_(acc[m][q] + sb2[j]);
            }
        }
    }
    __syncthreads();

    // sym -> ia ; deg/clus (stride 121 -> conflict-free transpose)
    float* dia = ia + (size_t)bk*NN2;
    for (int e4 = t; e4 < NN2/4; e4 += 512){
        int e = e4*4;
        int i = e / NN_, j0 = e - i*NN_;
        float4 v;
        v.x = 0.5f*(sA[i*121+j0+0] + sA[(j0+0)*121+i]);
        v.y = 0.5f*(sA[i*121+j0+1] + sA[(j0+1)*121+i]);
        v.z = 0.5f*(sA[i*121+j0+2] + sA[(j0+2)*121+i]);
        v.w = 0.5f*(sA[i*121+j0+3] + sA[(j0+3)*121+i]);
        *(float4*)&dia[e] = v;
    }
    if (t < 464){
        int r = t >> 2, q = t & 3;
        float tri = 0.f, dg = 0.f;
        for (int jj = 0; jj < 29; ++jj){
            int j = q*29 + jj;
            float v = 0.5f*(sA[r*121+j] + sA[j*121+r]);
            tri = fmaf(v, v, tri);
            dg += (v > 0.f) ? 1.f : 0.f;
        }
        tri += __shfl_xor(tri,1); tri += __shfl_xor(tri,2);
        dg  += __shfl_xor(dg,1);  dg  += __shfl_xor(dg,2);
        if (q == 0){
            deg_out[(size_t)bk*NN_ + r]  = dg;
            clus_out[(size_t)bk*NN_ + r] = tri / (dg*dg + 1e-8f);
        }
    }
}

// ---------------- graph stats (incl. band mean/std) + graph linear (r7) ----------------
__global__ __launch_bounds__(256) void k_gstats_lin(const float* __restrict__ band,
    const float* __restrict__ deg, const float* __restrict__ clus,
    const float* __restrict__ dens, const float* __restrict__ stren,
    const float* __restrict__ Wc, const float* __restrict__ bc,
    float* __restrict__ gfo, float* __restrict__ aux)
{
    int b = blockIdx.x, t = threadIdx.x;
    __shared__ float sGf[152];
    __shared__ float sPs[18*14*4];
    __shared__ float sPq[18*14*4];
    __shared__ float sA[4], sB[4];

    if (t < 252){
        int fq = t % 18, g = t / 18;
        float4 s = make_float4(0,0,0,0), q = make_float4(0,0,0,0);
        const float* base = band + (size_t)b*(KN*NF);
        for (int nk = g; nk < KN; nk += 14){
            float4 v = *(const float4*)&base[nk*NF + fq*4];
            s.x += v.x; s.y += v.y; s.z += v.z; s.w += v.w;
            q.x = fmaf(v.x,v.x,q.x); q.y = fmaf(v.y,v.y,q.y);
            q.z = fmaf(v.z,v.z,q.z); q.w = fmaf(v.w,v.w,q.w);
        }
        int idx = (fq*14 + g)*4;
        *(float4*)&sPs[idx] = s;
        *(float4*)&sPq[idx] = q;
    }
    __syncthreads();
    if (t < NF){
        int fq = t >> 2, e = t & 3;
        float S = 0.f, Q = 0.f;
        for (int g = 0; g < 14; ++g){ S += sPs[(fq*14+g)*4+e]; Q += sPq[(fq*14+g)*4+e]; }
        float mean = S * (1.0f/(float)KN);
        float var = fmaxf((Q - S*mean)/((float)KN - 1.0f), 0.0f);
        sGf[t] = mean;
        sGf[NF + t] = sqrtf(var);
    }
    __syncthreads();

    float s = 0.f, ss = 0.f;
    for (int e = t; e < KN; e += 256){ float v = deg[(size_t)b*KN + e]; s += v; ss += v*v; }
    #pragma unroll
    for (int d = 1; d < 64; d <<= 1){ s += __shfl_xor(s,d); ss += __shfl_xor(ss,d); }
    if ((t & 63) == 0){ sA[t>>6] = s; sB[t>>6] = ss; }
    __syncthreads();
    if (t == 0){
        float S0 = sA[0]+sA[1]+sA[2]+sA[3], S1 = sB[0]+sB[1]+sB[2]+sB[3];
        float Mv = (float)KN, mean = S0/Mv;
        float var = fmaxf((S1 - S0*mean)/(Mv - 1.0f), 0.0f);
        sGf[144] = mean; sGf[145] = sqrtf(var);
        aux[b] = S0;
    }
    __syncthreads();

    s = 0.f; ss = 0.f;
    for (int e = t; e < KN; e += 256){ float v = clus[(size_t)b*KN + e]; s += v; ss += v*v; }
    #pragma unroll
    for (int d = 1; d < 64; d <<= 1){ s += __shfl_xor(s,d); ss += __shfl_xor(ss,d); }
    if ((t & 63) == 0){ sA[t>>6] = s; sB[t>>6] = ss; }
    __syncthreads();
    if (t == 0){
        float S0 = sA[0]+sA[1]+sA[2]+sA[3], S1 = sB[0]+sB[1]+sB[2]+sB[3];
        float Mv = (float)KN, mean = S0/Mv;
        float var = fmaxf((S1 - S0*mean)/(Mv - 1.0f), 0.0f);
        sGf[146] = mean; sGf[147] = sqrtf(var);
    }
    __syncthreads();

    s = 0.f; ss = 0.f;
    for (int e = t; e < NN_; e += 256){ s += dens[(size_t)b*NN_ + e]; ss += stren[(size_t)b*NN_ + e]; }
    #pragma unroll
    for (int d = 1; d < 64; d <<= 1){ s += __shfl_xor(s,d); ss += __shfl_xor(ss,d); }
    if ((t & 63) == 0){ sA[t>>6] = s; sB[t>>6] = ss; }
    __syncthreads();
    if (t == 0){
        float S0 = sA[0]+sA[1]+sA[2]+sA[3], S1 = sB[0]+sB[1]+sB[2]+sB[3];
        sGf[148] = S0 / (float)NN_;
        sGf[149] = S1 / (float)NN_;
        aux[128 + b] = S0 * 16.0f;
    }
    __syncthreads();

    if (t < 128){
        float acc = bc[t];
        const float* w = Wc + (size_t)t*150;
        for (int c = 0; c < 150; ++c) acc = fmaf(sGf[c], w[c], acc);
        gfo[(size_t)b*128 + t] = fmaxf(acc, 0.f);
    }
}

// ---------------- sparsity (fallback standalone) ----------------
__global__ __launch_bounds__(64) void k_sparsity(const float* __restrict__ aux, float* __restrict__ out3)
{
    int t = threadIdx.x;
    float a = aux[t] + aux[64 + t];
    float c = aux[128 + t] + aux[192 + t];
    #pragma unroll
    for (int d = 1; d < 64; d <<= 1){ a += __shfl_xor(a,d); c += __shfl_xor(c,d); }
    if (t == 0){
        const float it = 6889472.0f, jt = 237568.0f;
        float isp = 1.0f - a/it;
        float jsp = 1.0f - c/jt;
        out3[0] = isp; out3[1] = jsp;
        out3[2] = (isp*it + jsp*jt)/(it + jt);
    }
}

// ============ K4: unified assembly (grid-stride) + optional sparsity ============
__global__ __launch_bounds__(256) void k_uninf(const float* __restrict__ intra_adj,
    const float* __restrict__ inter_adj, const float* __restrict__ aux,
    float* __restrict__ uni, float* __restrict__ sp, int do_sp)
{
    if (do_sp && blockIdx.x == 0 && threadIdx.x < 64){
        int t = threadIdx.x;
        float a = aux[t] + aux[64 + t];
        float c = aux[128 + t] + aux[192 + t];
        #pragma unroll
        for (int d = 1; d < 64; d <<= 1){ a += __shfl_xor(a,d); c += __shfl_xor(c,d); }
        if (t == 0){
            const float it = 6889472.0f, jt = 237568.0f;
            float isp = 1.0f - a/it;
            float jsp = 1.0f - c/jt;
            sp[0] = isp; sp[1] = jsp;
            sp[2] = (isp*it + jt*0.0f + jsp*jt - jsp*jt + jsp*jt)/(it + jt) * 0.0f
                    + (isp*it + jsp*jt)/(it + jt);
        }
    }
    int gid = blockIdx.x*256 + threadIdx.x;
    int gsz = gridDim.x*256;
    for (int q = gid; q < UNQ; q += gsz){
        int row = q / 116;
        int cq  = q - row*116;
        int b = row / KN;
        int p = row - b*KN;
        int k1 = p / NN_;
        int i  = p - k1*NN_;
        int k2 = cq / 29;
        int j0 = cq*4 - k2*NN_;
        float4 v;
        if (k2 == k1){
            v = *(const float4*)&intra_adj[(((size_t)b*NK + k1)*NN_ + i)*NN_ + j0];
        } else {
            int d = i - j0;
            float val = 0.f;
            if (d >= 0 && d < 4)
                val = inter_adj[(((size_t)b*NN_ + i)*NK + k1)*NK + k2];
            v.x = (d==0)?val:0.f;
            v.y = (d==1)?val:0.f;
            v.z = (d==2)?val:0.f;
            v.w = (d==3)?val:0.f;
        }
        *(float4*)&uni[(size_t)q*4] = v;
    }
}

extern "C" void kernel_launch(void* const* d_in, const int* in_sizes, int n_in,
                              void* d_out, int out_size, void* d_ws, size_t ws_size,
                              hipStream_t stream)
{
    const float* band = (const float*)d_in[0];
    const float* attn = (const float*)d_in[1];
    const float* thA  = (const float*)d_in[2];
    const float* thE  = (const float*)d_in[3];
    const float* fw   = (const float*)d_in[4];
    const float* iW1  = (const float*)d_in[5];
    const float* ib1  = (const float*)d_in[6];
    const float* iW2  = (const float*)d_in[7];
    const float* ib2  = (const float*)d_in[8];
    const float* eW1  = (const float*)d_in[9];
    const float* eb1  = (const float*)d_in[10];
    const float* eW2  = (const float*)d_in[11];
    const float* eb2  = (const float*)d_in[12];
    const float* cW   = (const float*)d_in[13];
    const float* cb   = (const float*)d_in[14];

    float* out = (float*)d_out;
    float* uni = out + OFF_UNI;
    float* nf  = out + OFF_NF;
    float* gfo = out + OFF_GF;
    float* ia  = out + OFF_IA;
    float* ie  = out + OFF_IE;
    float* sp  = out + OFF_SP;

    float* scr_sc    = uni + SCR_SC;
    float* scr_corr  = uni + SCR_CORR;
    float* scr_deg   = uni + SCR_DEG;
    float* scr_clus  = uni + SCR_CLUS;
    float* scr_dens  = uni + SCR_DENS;
    float* scr_stren = uni + SCR_STREN;

    int ws_ok = (ws_size >= 256*sizeof(float));
    float* aux = ws_ok ? (float*)d_ws : (uni + SCR_AUX);

    k_corr_inter<<<NB_CORR + NB_INTER + NB_COPY, 256, 0, stream>>>(
        band, attn, thE, fw, eW1, eb1, eW2, eb2,
        scr_corr, ie, scr_dens, scr_stren, nf);
    k_topk_mask<<<BK, 512, 0, stream>>>(scr_corr, thA, scr_sc);
    k_mlpsym<<<BK, 512, 0, stream>>>(scr_sc, iW1, ib1, iW2, ib2, ia, scr_deg, scr_clus);
    k_gstats_lin<<<NB, 256, 0, stream>>>(band, scr_deg, scr_clus, scr_dens, scr_stren,
                                         cW, cb, gfo, aux);
    if (!ws_ok)
        k_sparsity<<<1, 64, 0, stream>>>(aux, sp);
    k_uninf<<<2048, 256, 0, stream>>>(ia, ie, aux, uni, sp, ws_ok ? 1 : 0);
}

// Round 12
// 144.996 us; speedup vs baseline: 1.2474x; 1.0323x over previous
//
#include <hip/hip_runtime.h>
#include <math.h>

#define NB 128     // B
#define NN_ 116    // N
#define NK 4       // K
#define NF 72      // F
#define NS 8       // S
#define TOPK 10

#define BK (NB*NK)            // 512
#define BN (NB*NN_)           // 14848
#define NN2 (NN_*NN_)         // 13456
#define KN (NK*NN_)           // 464
#define ROWS (BK*NN_)         // 59392

// output section offsets (floats)
#define OFF_UNI 0
#define SZ_UNI (NB*KN*KN)                 // 27557888
#define OFF_NF (OFF_UNI + SZ_UNI)
#define SZ_NF (NB*KN*NF)                  // 4276224
#define OFF_GF (OFF_NF + SZ_NF)
#define SZ_GF (NB*128)
#define OFF_IA (OFF_GF + SZ_GF)
#define SZ_IA (NB*NK*NN_*NN_)             // 6889472
#define OFF_IE (OFF_IA + SZ_IA)
#define SZ_IE (NB*NN_*NK*NK)              // 237568
#define OFF_SP (OFF_IE + SZ_IE)

// scratch inside the unified region (consumed before k_uninf overwrites it)
#define SCR_CORR 0                        // corr (SZ_IA floats)
#define SCR_DEG (SCR_CORR + SZ_IA)
#define SCR_CLUS (SCR_DEG + ROWS)
#define SCR_DENS (SCR_CLUS + ROWS)
#define SCR_STREN (SCR_DENS + BN)
#define SCR_AUX (SCR_STREN + BN)          // 2*NB (fallback)

#define NFQ (SZ_NF/4)        // 1069056 float4 quads
#define UNQ (SZ_UNI/4)       // 6889472 float4 quads
#define NB_CORR 512
#define NB_INTER (BN/64)     // 232
#define NB_COPY 1044

__device__ __forceinline__ float sigmoidf_(float x){ return 1.0f/(1.0f+expf(-x)); }
__device__ __forceinline__ float dot4_(float4 a, float4 b){
    return fmaf(a.x,b.x, fmaf(a.y,b.y, fmaf(a.z,b.z, a.w*b.w)));
}
#define CLIP1(x) fminf(1.0f, fmaxf(-1.0f, (x)))

// ---- FAT1: blocks [0,512)=corr; [512,744)=inter; [744,1788)=nodefeat copy ----
__global__ __launch_bounds__(256, 1) void k_corr_inter(const float* __restrict__ band,
    const float* __restrict__ attn, const float* __restrict__ thadj2,
    const float* __restrict__ fwp,
    const float* __restrict__ eW1, const float* __restrict__ eb1,
    const float* __restrict__ eW2, const float* __restrict__ eb2,
    float* __restrict__ corr_out, float* __restrict__ inter_out,
    float* __restrict__ dens_out, float* __restrict__ stren_out,
    float* __restrict__ nf)
{
    __shared__ float sx[NF*120];
    __shared__ float smu[120], srs[120];
    __shared__ float sW1[128], sb1[32], sW2[128], sb2[4];
    __shared__ float sMat[256*4];
    int t = threadIdx.x;
    if (blockIdx.x < NB_CORR){
        int bk = blockIdx.x;
        int b = bk >> 2, k = bk & 3;
        const float* xin = band + ((size_t)b*NN_*NK + k)*NF;
        for (int e = t; e < NN_*NF; e += 256){
            int n = e / NF, f = e - n*NF;
            sx[f*120 + n] = xin[(size_t)n*NK*NF + f];
        }
        for (int e = t; e < NF*4; e += 256)
            sx[(e>>2)*120 + NN_ + (e&3)] = 0.0f;
        __syncthreads();
        if (t < NN_){
            float s = 0.f, ss = 0.f;
            for (int f = 0; f < NF; ++f){ float v = sx[f*120+t]; s += v; ss += v*v; }
            float mu = s * (1.0f/NF);
            float sd = sqrtf(fmaxf(ss - s*mu, 1e-8f));
            smu[t] = mu; srs[t] = 1.0f/sd;
        }
        __syncthreads();
        for (int e = t; e < NF*NN_; e += 256){
            int f = e / NN_, n = e - f*NN_;
            sx[f*120+n] = (sx[f*120+n] - smu[n]) * srs[n];
        }
        __syncthreads();
        float* dst = corr_out + (size_t)bk * NN2;
        if (t < 225){
            int ti = t / 15, tj = t - ti*15;
            int i0 = ti*8, j0 = tj*8;
            float acc[8][8] = {};
            for (int f = 0; f < NF; ++f){
                const float4 a0 = *(const float4*)&sx[f*120 + i0];
                const float4 a1 = *(const float4*)&sx[f*120 + i0 + 4];
                const float4 c0 = *(const float4*)&sx[f*120 + j0];
                const float4 c1 = *(const float4*)&sx[f*120 + j0 + 4];
                float av[8] = {a0.x,a0.y,a0.z,a0.w,a1.x,a1.y,a1.z,a1.w};
                float cv[8] = {c0.x,c0.y,c0.z,c0.w,c1.x,c1.y,c1.z,c1.w};
                #pragma unroll
                for (int r = 0; r < 8; ++r)
                    #pragma unroll
                    for (int c = 0; c < 8; ++c)
                        acc[r][c] = fmaf(av[r], cv[c], acc[r][c]);
            }
            #pragma unroll
            for (int r = 0; r < 8; ++r){
                int i = i0 + r;
                if (i < NN_){
                    float4 v0;
                    v0.x = CLIP1(acc[r][0]); v0.y = CLIP1(acc[r][1]);
                    v0.z = CLIP1(acc[r][2]); v0.w = CLIP1(acc[r][3]);
                    *(float4*)&dst[i*NN_ + j0] = v0;
                    if (j0 + 4 <= 112){
                        float4 v1;
                        v1.x = CLIP1(acc[r][4]); v1.y = CLIP1(acc[r][5]);
                        v1.z = CLIP1(acc[r][6]); v1.w = CLIP1(acc[r][7]);
                        *(float4*)&dst[i*NN_ + j0 + 4] = v1;
                    }
                }
            }
        }
    } else if (blockIdx.x < NB_CORR + NB_INTER){
        if (t < 128) sW1[t] = eW1[t];
        if (t < 32) sb1[t] = eb1[t];
        if (t >= 128 && t < 256) sW2[t-128] = eW2[t-128];
        if (t < 4) sb2[t] = eb2[t];
        __syncthreads();
        int l = t & 3;
        int il = t >> 2;
        size_t item = (size_t)(blockIdx.x - NB_CORR)*64 + il;

        const float* xr = band + item*(NK*NF) + l*NF;
        float s=0,p0=0,p1=0,p2=0,p3=0;
        for (int f = 0; f < NF; ++f){
            float v = xr[f];
            float v1=__shfl_xor(v,1), v2=__shfl_xor(v,2), v3=__shfl_xor(v,3);
            s += v; p0=fmaf(v,v,p0); p1=fmaf(v,v1,p1); p2=fmaf(v,v2,p2); p3=fmaf(v,v3,p3);
        }
        float mu = s*(1.0f/NF);
        float mu1=__shfl_xor(mu,1), mu2=__shfl_xor(mu,2), mu3=__shfl_xor(mu,3);
        float sd = sqrtf(fmaxf(p0 - s*mu, 1e-8f));
        float sd1=__shfl_xor(sd,1), sd2=__shfl_xor(sd,2), sd3=__shfl_xor(sd,3);
        float c0 = CLIP1((p0 - (float)NF*mu*mu )/(sd*sd +1e-8f));
        float c1 = CLIP1((p1 - (float)NF*mu*mu1)/(sd*sd1+1e-8f));
        float c2 = CLIP1((p2 - (float)NF*mu*mu2)/(sd*sd2+1e-8f));
        float c3 = CLIP1((p3 - (float)NF*mu*mu3)/(sd*sd3+1e-8f));

        const float* ar = attn + item*(NS*NK) + l;
        float as=0,q0=0,q1=0,q2=0,q3=0;
        #pragma unroll
        for (int s8 = 0; s8 < NS; ++s8){
            float v = ar[s8*NK];
            float v1=__shfl_xor(v,1), v2=__shfl_xor(v,2), v3=__shfl_xor(v,3);
            as += v; q0=fmaf(v,v,q0); q1=fmaf(v,v1,q1); q2=fmaf(v,v2,q2); q3=fmaf(v,v3,q3);
        }
        float am = as*(1.0f/NS);
        float am1=__shfl_xor(am,1), am2=__shfl_xor(am,2), am3=__shfl_xor(am,3);
        float ad = sqrtf(fmaxf(q0 - as*am, 1e-8f));
        float ad1=__shfl_xor(ad,1), ad2=__shfl_xor(ad,2), ad3=__shfl_xor(ad,3);
        float a0 = CLIP1((q0 - (float)NS*am*am )/(ad*ad +1e-8f));
        float a1 = CLIP1((q1 - (float)NS*am*am1)/(ad*ad1+1e-8f));
        float a2 = CLIP1((q2 - (float)NS*am*am2)/(ad*ad2+1e-8f));
        float a3 = CLIP1((q3 - (float)NS*am*am3)/(ad*ad3+1e-8f));

        float fwv = sigmoidf_(fwp[0]);
        float g0 = fwv*c0 + (1.0f-fwv)*a0;
        float g1 = fwv*c1 + (1.0f-fwv)*a1;
        float g2 = fwv*c2 + (1.0f-fwv)*a2;
        float g3 = fwv*c3 + (1.0f-fwv)*a3;
        float th2 = 0.2f + sigmoidf_(thadj2[0])*0.2f;
        float m0 = (fabsf(g0)>th2)?g0:0.f;
        float m1 = (fabsf(g1)>th2)?g1:0.f;
        float m2 = (fabsf(g2)>th2)?g2:0.f;
        float m3 = (fabsf(g3)>th2)?g3:0.f;

        sMat[il*16 + l*4 + (l^0)] = m0;
        sMat[il*16 + l*4 + (l^1)] = m1;
        sMat[il*16 + l*4 + (l^2)] = m2;
        sMat[il*16 + l*4 + (l^3)] = m3;
        __syncthreads();
        float x0 = fmaxf(0.5f*(sMat[il*16 + l*4 + 0] + sMat[il*16 + 0*4 + l]), 0.f);
        float x1 = fmaxf(0.5f*(sMat[il*16 + l*4 + 1] + sMat[il*16 + 1*4 + l]), 0.f);
        float x2 = fmaxf(0.5f*(sMat[il*16 + l*4 + 2] + sMat[il*16 + 2*4 + l]), 0.f);
        float x3 = fmaxf(0.5f*(sMat[il*16 + l*4 + 3] + sMat[il*16 + 3*4 + l]), 0.f);

        float h[32];
        #pragma unroll
        for (int o = 0; o < 32; ++o){
            float acc = sb1[o];
            acc = fmaf(sW1[o*4+0], x0, acc);
            acc = fmaf(sW1[o*4+1], x1, acc);
            acc = fmaf(sW1[o*4+2], x2, acc);
            acc = fmaf(sW1[o*4+3], x3, acc);
            h[o] = fmaxf(acc, 0.f);
        }
        float o0=sb2[0], o1=sb2[1], o2=sb2[2], o3=sb2[3];
        #pragma unroll
        for (int o = 0; o < 32; ++o){
            float hv = h[o];
            o0 = fmaf(sW2[0*32+o], hv, o0);
            o1 = fmaf(sW2[1*32+o], hv, o1);
            o2 = fmaf(sW2[2*32+o], hv, o2);
            o3 = fmaf(sW2[3*32+o], hv, o3);
        }
        o0 = sigmoidf_(o0); o1 = sigmoidf_(o1); o2 = sigmoidf_(o2); o3 = sigmoidf_(o3);
        __syncthreads();
        sMat[il*16 + l*4 + 0] = o0;
        sMat[il*16 + l*4 + 1] = o1;
        sMat[il*16 + l*4 + 2] = o2;
        sMat[il*16 + l*4 + 3] = o3;
        __syncthreads();
        float y0 = 0.5f*(o0 + sMat[il*16 + 0*4 + l]);
        float y1 = 0.5f*(o1 + sMat[il*16 + 1*4 + l]);
        float y2 = 0.5f*(o2 + sMat[il*16 + 2*4 + l]);
        float y3 = 0.5f*(o3 + sMat[il*16 + 3*4 + l]);
        *(float4*)&inter_out[item*16 + l*4] = make_float4(y0,y1,y2,y3);

        float cnt = ((y0>0.f)?1.f:0.f) + ((y1>0.f)?1.f:0.f) + ((y2>0.f)?1.f:0.f) + ((y3>0.f)?1.f:0.f);
        float sum = y0+y1+y2+y3;
        cnt += __shfl_xor(cnt,1); cnt += __shfl_xor(cnt,2);
        sum += __shfl_xor(sum,1); sum += __shfl_xor(sum,2);
        if (l == 0){
            dens_out[item]  = cnt * (1.0f/16.0f);
            stren_out[item] = sum * (1.0f/16.0f);
        }
    } else {
        int gid = (blockIdx.x - NB_CORR - NB_INTER)*256 + t;
        int gsz = NB_COPY*256;
        for (int q = gid; q < NFQ; q += gsz){
            int fq = q % 18;
            int rest = q / 18;
            int b = rest / KN;
            int p = rest - b*KN;
            int k = p / NN_;
            int n = p - k*NN_;
            float4 v = *(const float4*)&band[(((size_t)b*NN_ + n)*NK + k)*NF + fq*4];
            *(float4*)&nf[(size_t)q*4] = v;
        }
    }
}

// ============ K2: topk + mask + MLP + sym + deg/clus, one block per (b,k) ============
// LDS (floats): LA=0 (14036: corr[116][121] -> sc[116][116] -> intra[116][121]);
// LB=14036 (9728: W1[64][116] -> W2[128][76]); LH=23764 (7888: [116][68], overlaid
// first by sTop[464*10] u32); LB1=31652 (64); LB2=31716 (128); LKM=31844 (464 u32).
// Total 32308 floats = 129.2 KB -> 1 block/CU, 8 waves. All phases parallel-dense.
// Bank audit: corr transpose reads stride 121 (25 mod 32, gcd=1 -> all banks);
// mask writes stride 116 consecutive-e (conflict-free); mlp reads = r6-proven patterns.
__global__ __launch_bounds__(512) void k_topk_mlpsym(const float* __restrict__ corr,
    const float* __restrict__ thadj,
    const float* __restrict__ W1, const float* __restrict__ b1,
    const float* __restrict__ W2, const float* __restrict__ b2,
    float* __restrict__ ia, float* __restrict__ deg_out, float* __restrict__ clus_out)
{
    __shared__ float smem[32308];
    float* sA  = smem;             // corr[121] -> sc[116] -> intra[121]
    float* sB  = smem + 14036;     // W1 then W2
    float* sH  = smem + 23764;     // [116][68]; sTop overlay first
    float* sb1 = smem + 31652;
    float* sb2 = smem + 31716;
    unsigned* sKm  = (unsigned*)(smem + 31844);
    unsigned* sTop = (unsigned*)sH;
    int bk = blockIdx.x, t = threadIdx.x;

    // P1: corr -> sA stride 121 (scalar stores); W1 -> sB; biases
    const float* src = corr + (size_t)bk*NN2;
    for (int e4 = t; e4 < NN2/4; e4 += 512){
        int e = e4*4;
        int i = e / 116, j = e - i*116;
        float4 v = *(const float4*)&src[e];
        sA[i*121 + j + 0] = v.x;
        sA[i*121 + j + 1] = v.y;
        sA[i*121 + j + 2] = v.z;
        sA[i*121 + j + 3] = v.w;
    }
    for (int e4 = t; e4 < 1856; e4 += 512)
        *(float4*)&sB[e4*4] = *(const float4*)&W1[e4*4];
    if (t < 64) sb1[t] = b1[t];
    if (t >= 64 && t < 192) sb2[t-64] = (t-64 < NN_) ? b2[t-64] : 0.0f;
    __syncthreads();

    // P2: top-10 per row, 4 threads/row, packed keys
    if (t < 464){
        int r = t >> 2, q = t & 3;
        const float* row = &sA[r*121 + q*29];
        int jbase = q*29;
        unsigned tv[TOPK];
        #pragma unroll
        for (int p = 0; p < TOPK; ++p) tv[p] = 0u;
        for (int jj = 0; jj < 29; ++jj){
            float c = fabsf(row[jj]);
            unsigned u = (__float_as_uint(c) & 0xFFFFFF80u) | (unsigned)(127 - (jbase + jj));
            #pragma unroll
            for (int p = 0; p < TOPK; ++p){
                unsigned old = tv[p];
                bool gt = u > old;
                tv[p] = gt ? u : old;
                u = gt ? old : u;
            }
        }
        #pragma unroll
        for (int p = 0; p < TOPK; ++p) sTop[t*10 + p] = tv[p];
    }
    __syncthreads();

    // P3: 4-way merge -> bitmask
    if (t < NN_){
        const unsigned* L0 = &sTop[(4*t+0)*10];
        const unsigned* L1 = &sTop[(4*t+1)*10];
        const unsigned* L2 = &sTop[(4*t+2)*10];
        const unsigned* L3 = &sTop[(4*t+3)*10];
        int i0=0, i1=0, i2=0, i3=0;
        unsigned m0=0,m1=0,m2=0,m3=0;
        #pragma unroll
        for (int p = 0; p < TOPK; ++p){
            unsigned u0 = L0[i0], u1 = L1[i1], u2 = L2[i2], u3 = L3[i3];
            unsigned ua = u0 > u1 ? u0 : u1;
            unsigned ub = u2 > u3 ? u2 : u3;
            unsigned u  = ua > ub ? ua : ub;
            if (u == u0) ++i0; else if (u == u1) ++i1; else if (u == u2) ++i2; else ++i3;
            int j = 127 - (int)(u & 127u);
            unsigned bit = 1u << (j & 31);
            int w = j >> 5;
            if (w == 0) m0 |= bit; else if (w == 1) m1 |= bit; else if (w == 2) m2 |= bit; else m3 |= bit;
        }
        sKm[t*4+0]=m0; sKm[t*4+1]=m1; sKm[t*4+2]=m2; sKm[t*4+3]=m3;
    }
    __syncthreads();

    // P4: sc = relu(sym(corr*tmask*kmask)); register-buffer then rewrite at stride 116
    {
        float th = 0.1f + sigmoidf_(thadj[0]) * 0.2f;
        float vb[27];
        #pragma unroll
        for (int it = 0; it < 27; ++it){
            int e = t + it*512;
            float v = 0.0f;
            if (e < NN2){
                int i = e / 116, j = e - i*116;
                float cij = sA[i*121 + j];
                float cji = sA[j*121 + i];
                bool kij = (sKm[i*4 + (j>>5)] >> (j&31)) & 1u;
                bool kji = (sKm[j*4 + (i>>5)] >> (i&31)) & 1u;
                float mij = (fabsf(cij) > th && kij) ? cij : 0.0f;
                float mji = (fabsf(cji) > th && kji) ? cji : 0.0f;
                v = fmaxf(0.5f*(mij+mji), 0.0f);
            }
            vb[it] = v;
        }
        __syncthreads();
        #pragma unroll
        for (int it = 0; it < 27; ++it){
            int e = t + it*512;
            if (e < NN2) sA[e] = vb[it];
        }
    }
    __syncthreads();

    // P5: mlp1: H[116][64] = relu(sc @ W1^T + b1); rows rg+29m, outs og+16n
    if (t < 464){
        int rg = t >> 4, og = t & 15;
        float acc[4][4] = {};
        for (int j4 = 0; j4 < 29; ++j4){
            float4 s[4], w[4];
            #pragma unroll
            for (int m = 0; m < 4; ++m) s[m] = *(const float4*)&sA[(rg+29*m)*116 + j4*4];
            #pragma unroll
            for (int n = 0; n < 4; ++n) w[n] = *(const float4*)&sB[(og+16*n)*116 + j4*4];
            #pragma unroll
            for (int m = 0; m < 4; ++m)
                #pragma unroll
                for (int n = 0; n < 4; ++n)
                    acc[m][n] += dot4_(s[m], w[n]);
        }
        #pragma unroll
        for (int m = 0; m < 4; ++m)
            #pragma unroll
            for (int n = 0; n < 4; ++n)
                sH[(rg+29*m)*68 + og+16*n] = fmaxf(acc[m][n] + sb1[og+16*n], 0.0f);
    }
    __syncthreads();

    // P6: W2 -> sB [128][76] (zero-padded rows >= 116)
    for (int e = t; e < 128*64; e += 512){
        int j = e >> 6, o = e & 63;
        sB[j*76 + o] = (j < NN_) ? W2[e] : 0.0f;
    }
    __syncthreads();

    // P7: intra = sigmoid(H @ W2^T + b2) -> sA at stride 121
    if (t < 464){
        int rg = t >> 4, jg = t & 15;
        float acc[4][8] = {};
        for (int o4 = 0; o4 < 16; ++o4){
            float4 h[4], w[8];
            #pragma unroll
            for (int m = 0; m < 4; ++m) h[m] = *(const float4*)&sH[(rg+29*m)*68 + o4*4];
            #pragma unroll
            for (int q = 0; q < 8; ++q) w[q] = *(const float4*)&sB[(jg+16*q)*76 + o4*4];
            #pragma unroll
            for (int m = 0; m < 4; ++m)
                #pragma unroll
                for (int q = 0; q < 8; ++q)
                    acc[m][q] += dot4_(h[m], w[q]);
        }
        #pragma unroll
        for (int m = 0; m < 4; ++m){
            int row = rg + 29*m;
            #pragma unroll
            for (int q = 0; q < 8; ++q){
                int j = jg + 16*q;
                if (j < NN_)
                    sA[row*121 + j] = sigmoidf_(acc[m][q] + sb2[j]);
            }
        }
    }
    __syncthreads();

    // P8: sym -> ia ; deg/clus (stride 121 transpose, conflict-free)
    float* dia = ia + (size_t)bk*NN2;
    for (int e4 = t; e4 < NN2/4; e4 += 512){
        int e = e4*4;
        int i = e / 116, j0 = e - i*116;
        float4 v;
        v.x = 0.5f*(sA[i*121+j0+0] + sA[(j0+0)*121+i]);
        v.y = 0.5f*(sA[i*121+j0+1] + sA[(j0+1)*121+i]);
        v.z = 0.5f*(sA[i*121+j0+2] + sA[(j0+2)*121+i]);
        v.w = 0.5f*(sA[i*121+j0+3] + sA[(j0+3)*121+i]);
        *(float4*)&dia[e] = v;
    }
    if (t < 464){
        int r = t >> 2, q = t & 3;
        float tri = 0.f, dg = 0.f;
        for (int jj = 0; jj < 29; ++jj){
            int j = q*29 + jj;
            float v = 0.5f*(sA[r*121+j] + sA[j*121+r]);
            tri = fmaf(v, v, tri);
            dg += (v > 0.f) ? 1.f : 0.f;
        }
        tri += __shfl_xor(tri,1); tri += __shfl_xor(tri,2);
        dg  += __shfl_xor(dg,1);  dg  += __shfl_xor(dg,2);
        if (q == 0){
            deg_out[(size_t)bk*NN_ + r]  = dg;
            clus_out[(size_t)bk*NN_ + r] = tri / (dg*dg + 1e-8f);
        }
    }
}

// ---------------- graph stats (incl. band mean/std) + graph linear (r7) ----------------
__global__ __launch_bounds__(256) void k_gstats_lin(const float* __restrict__ band,
    const float* __restrict__ deg, const float* __restrict__ clus,
    const float* __restrict__ dens, const float* __restrict__ stren,
    const float* __restrict__ Wc, const float* __restrict__ bc,
    float* __restrict__ gfo, float* __restrict__ aux)
{
    int b = blockIdx.x, t = threadIdx.x;
    __shared__ float sGf[152];
    __shared__ float sPs[18*14*4];
    __shared__ float sPq[18*14*4];
    __shared__ float sA[4], sB[4];

    if (t < 252){
        int fq = t % 18, g = t / 18;
        float4 s = make_float4(0,0,0,0), q = make_float4(0,0,0,0);
        const float* base = band + (size_t)b*(KN*NF);
        for (int nk = g; nk < KN; nk += 14){
            float4 v = *(const float4*)&base[nk*NF + fq*4];
            s.x += v.x; s.y += v.y; s.z += v.z; s.w += v.w;
            q.x = fmaf(v.x,v.x,q.x); q.y = fmaf(v.y,v.y,q.y);
            q.z = fmaf(v.z,v.z,q.z); q.w = fmaf(v.w,v.w,q.w);
        }
        int idx = (fq*14 + g)*4;
        *(float4*)&sPs[idx] = s;
        *(float4*)&sPq[idx] = q;
    }
    __syncthreads();
    if (t < NF){
        int fq = t >> 2, e = t & 3;
        float S = 0.f, Q = 0.f;
        for (int g = 0; g < 14; ++g){ S += sPs[(fq*14+g)*4+e]; Q += sPq[(fq*14+g)*4+e]; }
        float mean = S * (1.0f/(float)KN);
        float var = fmaxf((Q - S*mean)/((float)KN - 1.0f), 0.0f);
        sGf[t] = mean;
        sGf[NF + t] = sqrtf(var);
    }
    __syncthreads();

    float s = 0.f, ss = 0.f;
    for (int e = t; e < KN; e += 256){ float v = deg[(size_t)b*KN + e]; s += v; ss += v*v; }
    #pragma unroll
    for (int d = 1; d < 64; d <<= 1){ s += __shfl_xor(s,d); ss += __shfl_xor(ss,d); }
    if ((t & 63) == 0){ sA[t>>6] = s; sB[t>>6] = ss; }
    __syncthreads();
    if (t == 0){
        float S0 = sA[0]+sA[1]+sA[2]+sA[3], S1 = sB[0]+sB[1]+sB[2]+sB[3];
        float Mv = (float)KN, mean = S0/Mv;
        float var = fmaxf((S1 - S0*mean)/(Mv - 1.0f), 0.0f);
        sGf[144] = mean; sGf[145] = sqrtf(var);
        aux[b] = S0;
    }
    __syncthreads();

    s = 0.f; ss = 0.f;
    for (int e = t; e < KN; e += 256){ float v = clus[(size_t)b*KN + e]; s += v; ss += v*v; }
    #pragma unroll
    for (int d = 1; d < 64; d <<= 1){ s += __shfl_xor(s,d); ss += __shfl_xor(ss,d); }
    if ((t & 63) == 0){ sA[t>>6] = s; sB[t>>6] = ss; }
    __syncthreads();
    if (t == 0){
        float S0 = sA[0]+sA[1]+sA[2]+sA[3], S1 = sB[0]+sB[1]+sB[2]+sB[3];
        float Mv = (float)KN, mean = S0/Mv;
        float var = fmaxf((S1 - S0*mean)/(Mv - 1.0f), 0.0f);
        sGf[146] = mean; sGf[147] = sqrtf(var);
    }
    __syncthreads();

    s = 0.f; ss = 0.f;
    for (int e = t; e < NN_; e += 256){ s += dens[(size_t)b*NN_ + e]; ss += stren[(size_t)b*NN_ + e]; }
    #pragma unroll
    for (int d = 1; d < 64; d <<= 1){ s += __shfl_xor(s,d); ss += __shfl_xor(ss,d); }
    if ((t & 63) == 0){ sA[t>>6] = s; sB[t>>6] = ss; }
    __syncthreads();
    if (t == 0){
        float S0 = sA[0]+sA[1]+sA[2]+sA[3], S1 = sB[0]+sB[1]+sB[2]+sB[3];
        sGf[148] = S0 / (float)NN_;
        sGf[149] = S1 / (float)NN_;
        aux[128 + b] = S0 * 16.0f;
    }
    __syncthreads();

    if (t < 128){
        float acc = bc[t];
        const float* w = Wc + (size_t)t*150;
        for (int c = 0; c < 150; ++c) acc = fmaf(sGf[c], w[c], acc);
        gfo[(size_t)b*128 + t] = fmaxf(acc, 0.f);
    }
}

// ---------------- sparsity (fallback standalone) ----------------
__global__ __launch_bounds__(64) void k_sparsity(const float* __restrict__ aux, float* __restrict__ out3)
{
    int t = threadIdx.x;
    float a = aux[t] + aux[64 + t];
    float c = aux[128 + t] + aux[192 + t];
    #pragma unroll
    for (int d = 1; d < 64; d <<= 1){ a += __shfl_xor(a,d); c += __shfl_xor(c,d); }
    if (t == 0){
        const float it = 6889472.0f, jt = 237568.0f;
        float isp = 1.0f - a/it;
        float jsp = 1.0f - c/jt;
        out3[0] = isp; out3[1] = jsp;
        out3[2] = (isp*it + jsp*jt)/(it + jt);
    }
}

// ============ K4: unified assembly (grid-stride) + optional sparsity ============
__global__ __launch_bounds__(256) void k_uninf(const float* __restrict__ intra_adj,
    const float* __restrict__ inter_adj, const float* __restrict__ aux,
    float* __restrict__ uni, float* __restrict__ sp, int do_sp)
{
    if (do_sp && blockIdx.x == 0 && threadIdx.x < 64){
        int t = threadIdx.x;
        float a = aux[t] + aux[64 + t];
        float c = aux[128 + t] + aux[192 + t];
        #pragma unroll
        for (int d = 1; d < 64; d <<= 1){ a += __shfl_xor(a,d); c += __shfl_xor(c,d); }
        if (t == 0){
            const float it = 6889472.0f, jt = 237568.0f;
            float isp = 1.0f - a/it;
            float jsp = 1.0f - c/jt;
            sp[0] = isp; sp[1] = jsp;
            sp[2] = (isp*it + jsp*jt)/(it + jt);
        }
    }
    int gid = blockIdx.x*256 + threadIdx.x;
    int gsz = gridDim.x*256;
    for (int q = gid; q < UNQ; q += gsz){
        int row = q / 116;
        int cq  = q - row*116;
        int b = row / KN;
        int p = row - b*KN;
        int k1 = p / NN_;
        int i  = p - k1*NN_;
        int k2 = cq / 29;
        int j0 = cq*4 - k2*NN_;
        float4 v;
        if (k2 == k1){
            v = *(const float4*)&intra_adj[(((size_t)b*NK + k1)*NN_ + i)*NN_ + j0];
        } else {
            int d = i - j0;
            float val = 0.f;
            if (d >= 0 && d < 4)
                val = inter_adj[(((size_t)b*NN_ + i)*NK + k1)*NK + k2];
            v.x = (d==0)?val:0.f;
            v.y = (d==1)?val:0.f;
            v.z = (d==2)?val:0.f;
            v.w = (d==3)?val:0.f;
        }
        *(float4*)&uni[(size_t)q*4] = v;
    }
}

extern "C" void kernel_launch(void* const* d_in, const int* in_sizes, int n_in,
                              void* d_out, int out_size, void* d_ws, size_t ws_size,
                              hipStream_t stream)
{
    const float* band = (const float*)d_in[0];
    const float* attn = (const float*)d_in[1];
    const float* thA  = (const float*)d_in[2];
    const float* thE  = (const float*)d_in[3];
    const float* fw   = (const float*)d_in[4];
    const float* iW1  = (const float*)d_in[5];
    const float* ib1  = (const float*)d_in[6];
    const float* iW2  = (const float*)d_in[7];
    const float* ib2  = (const float*)d_in[8];
    const float* eW1  = (const float*)d_in[9];
    const float* eb1  = (const float*)d_in[10];
    const float* eW2  = (const float*)d_in[11];
    const float* eb2  = (const float*)d_in[12];
    const float* cW   = (const float*)d_in[13];
    const float* cb   = (const float*)d_in[14];

    float* out = (float*)d_out;
    float* uni = out + OFF_UNI;
    float* nf  = out + OFF_NF;
    float* gfo = out + OFF_GF;
    float* ia  = out + OFF_IA;
    float* ie  = out + OFF_IE;
    float* sp  = out + OFF_SP;

    float* scr_corr  = uni + SCR_CORR;
    float* scr_deg   = uni + SCR_DEG;
    float* scr_clus  = uni + SCR_CLUS;
    float* scr_dens  = uni + SCR_DENS;
    float* scr_stren = uni + SCR_STREN;

    int ws_ok = (ws_size >= 256*sizeof(float));
    float* aux = ws_ok ? (float*)d_ws : (uni + SCR_AUX);

    k_corr_inter<<<NB_CORR + NB_INTER + NB_COPY, 256, 0, stream>>>(
        band, attn, thE, fw, eW1, eb1, eW2, eb2,
        scr_corr, ie, scr_dens, scr_stren, nf);
    k_topk_mlpsym<<<BK, 512, 0, stream>>>(scr_corr, thA, iW1, ib1, iW2, ib2,
                                          ia, scr_deg, scr_clus);
    k_gstats_lin<<<NB, 256, 0, stream>>>(band, scr_deg, scr_clus, scr_dens, scr_stren,
                                         cW, cb, gfo, aux);
    if (!ws_ok)
        k_sparsity<<<1, 64, 0, stream>>>(aux, sp);
    k_uninf<<<2048, 256, 0, stream>>>(ia, ie, aux, uni, sp, ws_ok ? 1 : 0);
}

// Round 13
// 139.671 us; speedup vs baseline: 1.2949x; 1.0381x over previous
//
#include <hip/hip_runtime.h>
#include <math.h>

#define NB 128     // B
#define NN_ 116    // N
#define NK 4       // K
#define NF 72      // F
#define NS 8       // S
#define TOPK 10

#define BK (NB*NK)            // 512
#define BN (NB*NN_)           // 14848
#define NN2 (NN_*NN_)         // 13456
#define KN (NK*NN_)           // 464
#define ROWS (BK*NN_)         // 59392

// output section offsets (floats)
#define OFF_UNI 0
#define SZ_UNI (NB*KN*KN)                 // 27557888
#define OFF_NF (OFF_UNI + SZ_UNI)
#define SZ_NF (NB*KN*NF)                  // 4276224
#define OFF_GF (OFF_NF + SZ_NF)
#define SZ_GF (NB*128)
#define OFF_IA (OFF_GF + SZ_GF)
#define SZ_IA (NB*NK*NN_*NN_)             // 6889472
#define OFF_IE (OFF_IA + SZ_IA)
#define SZ_IE (NB*NN_*NK*NK)              // 237568
#define OFF_SP (OFF_IE + SZ_IE)

// scratch inside the unified region (consumed before k_uninf overwrites it)
#define SCR_CORR 0                        // corr (SZ_IA floats)
#define SCR_DEG (SCR_CORR + SZ_IA)
#define SCR_CLUS (SCR_DEG + ROWS)
#define SCR_DENS (SCR_CLUS + ROWS)
#define SCR_STREN (SCR_DENS + BN)
#define SCR_AUX (SCR_STREN + BN)          // 2*NB (fallback)

#define NFQ (SZ_NF/4)        // 1069056 float4 quads
#define UNQ (SZ_UNI/4)       // 6889472 float4 quads
#define NB_CORR 512
#define NB_INTER (BN/64)     // 232
#define NB_COPY 1044

__device__ __forceinline__ float sigmoidf_(float x){ return 1.0f/(1.0f+expf(-x)); }
__device__ __forceinline__ float dot4_(float4 a, float4 b){
    return fmaf(a.x,b.x, fmaf(a.y,b.y, fmaf(a.z,b.z, a.w*b.w)));
}
#define CLIP1(x) fminf(1.0f, fmaxf(-1.0f, (x)))

// ---- FAT1: blocks [0,512)=corr; [512,744)=inter; [744,1788)=nodefeat copy ----
__global__ __launch_bounds__(256, 1) void k_corr_inter(const float* __restrict__ band,
    const float* __restrict__ attn, const float* __restrict__ thadj2,
    const float* __restrict__ fwp,
    const float* __restrict__ eW1, const float* __restrict__ eb1,
    const float* __restrict__ eW2, const float* __restrict__ eb2,
    float* __restrict__ corr_out, float* __restrict__ inter_out,
    float* __restrict__ dens_out, float* __restrict__ stren_out,
    float* __restrict__ nf)
{
    __shared__ float sx[NF*120];
    __shared__ float smu[120], srs[120];
    __shared__ float sW1[128], sb1[32], sW2[128], sb2[4];
    __shared__ float sMat[256*4];
    int t = threadIdx.x;
    if (blockIdx.x < NB_CORR){
        int bk = blockIdx.x;
        int b = bk >> 2, k = bk & 3;
        const float* xin = band + ((size_t)b*NN_*NK + k)*NF;
        for (int e = t; e < NN_*NF; e += 256){
            int n = e / NF, f = e - n*NF;
            sx[f*120 + n] = xin[(size_t)n*NK*NF + f];
        }
        for (int e = t; e < NF*4; e += 256)
            sx[(e>>2)*120 + NN_ + (e&3)] = 0.0f;
        __syncthreads();
        if (t < NN_){
            float s = 0.f, ss = 0.f;
            for (int f = 0; f < NF; ++f){ float v = sx[f*120+t]; s += v; ss += v*v; }
            float mu = s * (1.0f/NF);
            float sd = sqrtf(fmaxf(ss - s*mu, 1e-8f));
            smu[t] = mu; srs[t] = 1.0f/sd;
        }
        __syncthreads();
        for (int e = t; e < NF*NN_; e += 256){
            int f = e / NN_, n = e - f*NN_;
            sx[f*120+n] = (sx[f*120+n] - smu[n]) * srs[n];
        }
        __syncthreads();
        float* dst = corr_out + (size_t)bk * NN2;
        if (t < 225){
            int ti = t / 15, tj = t - ti*15;
            int i0 = ti*8, j0 = tj*8;
            float acc[8][8] = {};
            for (int f = 0; f < NF; ++f){
                const float4 a0 = *(const float4*)&sx[f*120 + i0];
                const float4 a1 = *(const float4*)&sx[f*120 + i0 + 4];
                const float4 c0 = *(const float4*)&sx[f*120 + j0];
                const float4 c1 = *(const float4*)&sx[f*120 + j0 + 4];
                float av[8] = {a0.x,a0.y,a0.z,a0.w,a1.x,a1.y,a1.z,a1.w};
                float cv[8] = {c0.x,c0.y,c0.z,c0.w,c1.x,c1.y,c1.z,c1.w};
                #pragma unroll
                for (int r = 0; r < 8; ++r)
                    #pragma unroll
                    for (int c = 0; c < 8; ++c)
                        acc[r][c] = fmaf(av[r], cv[c], acc[r][c]);
            }
            #pragma unroll
            for (int r = 0; r < 8; ++r){
                int i = i0 + r;
                if (i < NN_){
                    float4 v0;
                    v0.x = CLIP1(acc[r][0]); v0.y = CLIP1(acc[r][1]);
                    v0.z = CLIP1(acc[r][2]); v0.w = CLIP1(acc[r][3]);
                    *(float4*)&dst[i*NN_ + j0] = v0;
                    if (j0 + 4 <= 112){
                        float4 v1;
                        v1.x = CLIP1(acc[r][4]); v1.y = CLIP1(acc[r][5]);
                        v1.z = CLIP1(acc[r][6]); v1.w = CLIP1(acc[r][7]);
                        *(float4*)&dst[i*NN_ + j0 + 4] = v1;
                    }
                }
            }
        }
    } else if (blockIdx.x < NB_CORR + NB_INTER){
        if (t < 128) sW1[t] = eW1[t];
        if (t < 32) sb1[t] = eb1[t];
        if (t >= 128 && t < 256) sW2[t-128] = eW2[t-128];
        if (t < 4) sb2[t] = eb2[t];
        __syncthreads();
        int l = t & 3;
        int il = t >> 2;
        size_t item = (size_t)(blockIdx.x - NB_CORR)*64 + il;

        const float* xr = band + item*(NK*NF) + l*NF;
        float s=0,p0=0,p1=0,p2=0,p3=0;
        for (int f = 0; f < NF; ++f){
            float v = xr[f];
            float v1=__shfl_xor(v,1), v2=__shfl_xor(v,2), v3=__shfl_xor(v,3);
            s += v; p0=fmaf(v,v,p0); p1=fmaf(v,v1,p1); p2=fmaf(v,v2,p2); p3=fmaf(v,v3,p3);
        }
        float mu = s*(1.0f/NF);
        float mu1=__shfl_xor(mu,1), mu2=__shfl_xor(mu,2), mu3=__shfl_xor(mu,3);
        float sd = sqrtf(fmaxf(p0 - s*mu, 1e-8f));
        float sd1=__shfl_xor(sd,1), sd2=__shfl_xor(sd,2), sd3=__shfl_xor(sd,3);
        float c0 = CLIP1((p0 - (float)NF*mu*mu )/(sd*sd +1e-8f));
        float c1 = CLIP1((p1 - (float)NF*mu*mu1)/(sd*sd1+1e-8f));
        float c2 = CLIP1((p2 - (float)NF*mu*mu2)/(sd*sd2+1e-8f));
        float c3 = CLIP1((p3 - (float)NF*mu*mu3)/(sd*sd3+1e-8f));

        const float* ar = attn + item*(NS*NK) + l;
        float as=0,q0=0,q1=0,q2=0,q3=0;
        #pragma unroll
        for (int s8 = 0; s8 < NS; ++s8){
            float v = ar[s8*NK];
            float v1=__shfl_xor(v,1), v2=__shfl_xor(v,2), v3=__shfl_xor(v,3);
            as += v; q0=fmaf(v,v,q0); q1=fmaf(v,v1,q1); q2=fmaf(v,v2,q2); q3=fmaf(v,v3,q3);
        }
        float am = as*(1.0f/NS);
        float am1=__shfl_xor(am,1), am2=__shfl_xor(am,2), am3=__shfl_xor(am,3);
        float ad = sqrtf(fmaxf(q0 - as*am, 1e-8f));
        float ad1=__shfl_xor(ad,1), ad2=__shfl_xor(ad,2), ad3=__shfl_xor(ad,3);
        float a0 = CLIP1((q0 - (float)NS*am*am )/(ad*ad +1e-8f));
        float a1 = CLIP1((q1 - (float)NS*am*am1)/(ad*ad1+1e-8f));
        float a2 = CLIP1((q2 - (float)NS*am*am2)/(ad*ad2+1e-8f));
        float a3 = CLIP1((q3 - (float)NS*am*am3)/(ad*ad3+1e-8f));

        float fwv = sigmoidf_(fwp[0]);
        float g0 = fwv*c0 + (1.0f-fwv)*a0;
        float g1 = fwv*c1 + (1.0f-fwv)*a1;
        float g2 = fwv*c2 + (1.0f-fwv)*a2;
        float g3 = fwv*c3 + (1.0f-fwv)*a3;
        float th2 = 0.2f + sigmoidf_(thadj2[0])*0.2f;
        float m0 = (fabsf(g0)>th2)?g0:0.f;
        float m1 = (fabsf(g1)>th2)?g1:0.f;
        float m2 = (fabsf(g2)>th2)?g2:0.f;
        float m3 = (fabsf(g3)>th2)?g3:0.f;

        sMat[il*16 + l*4 + (l^0)] = m0;
        sMat[il*16 + l*4 + (l^1)] = m1;
        sMat[il*16 + l*4 + (l^2)] = m2;
        sMat[il*16 + l*4 + (l^3)] = m3;
        __syncthreads();
        float x0 = fmaxf(0.5f*(sMat[il*16 + l*4 + 0] + sMat[il*16 + 0*4 + l]), 0.f);
        float x1 = fmaxf(0.5f*(sMat[il*16 + l*4 + 1] + sMat[il*16 + 1*4 + l]), 0.f);
        float x2 = fmaxf(0.5f*(sMat[il*16 + l*4 + 2] + sMat[il*16 + 2*4 + l]), 0.f);
        float x3 = fmaxf(0.5f*(sMat[il*16 + l*4 + 3] + sMat[il*16 + 3*4 + l]), 0.f);

        float h[32];
        #pragma unroll
        for (int o = 0; o < 32; ++o){
            float acc = sb1[o];
            acc = fmaf(sW1[o*4+0], x0, acc);
            acc = fmaf(sW1[o*4+1], x1, acc);
            acc = fmaf(sW1[o*4+2], x2, acc);
            acc = fmaf(sW1[o*4+3], x3, acc);
            h[o] = fmaxf(acc, 0.f);
        }
        float o0=sb2[0], o1=sb2[1], o2=sb2[2], o3=sb2[3];
        #pragma unroll
        for (int o = 0; o < 32; ++o){
            float hv = h[o];
            o0 = fmaf(sW2[0*32+o], hv, o0);
            o1 = fmaf(sW2[1*32+o], hv, o1);
            o2 = fmaf(sW2[2*32+o], hv, o2);
            o3 = fmaf(sW2[3*32+o], hv, o3);
        }
        o0 = sigmoidf_(o0); o1 = sigmoidf_(o1); o2 = sigmoidf_(o2); o3 = sigmoidf_(o3);
        __syncthreads();
        sMat[il*16 + l*4 + 0] = o0;
        sMat[il*16 + l*4 + 1] = o1;
        sMat[il*16 + l*4 + 2] = o2;
        sMat[il*16 + l*4 + 3] = o3;
        __syncthreads();
        float y0 = 0.5f*(o0 + sMat[il*16 + 0*4 + l]);
        float y1 = 0.5f*(o1 + sMat[il*16 + 1*4 + l]);
        float y2 = 0.5f*(o2 + sMat[il*16 + 2*4 + l]);
        float y3 = 0.5f*(o3 + sMat[il*16 + 3*4 + l]);
        *(float4*)&inter_out[item*16 + l*4] = make_float4(y0,y1,y2,y3);

        float cnt = ((y0>0.f)?1.f:0.f) + ((y1>0.f)?1.f:0.f) + ((y2>0.f)?1.f:0.f) + ((y3>0.f)?1.f:0.f);
        float sum = y0+y1+y2+y3;
        cnt += __shfl_xor(cnt,1); cnt += __shfl_xor(cnt,2);
        sum += __shfl_xor(sum,1); sum += __shfl_xor(sum,2);
        if (l == 0){
            dens_out[item]  = cnt * (1.0f/16.0f);
            stren_out[item] = sum * (1.0f/16.0f);
        }
    } else {
        int gid = (blockIdx.x - NB_CORR - NB_INTER)*256 + t;
        int gsz = NB_COPY*256;
        for (int q = gid; q < NFQ; q += gsz){
            int fq = q % 18;
            int rest = q / 18;
            int b = rest / KN;
            int p = rest - b*KN;
            int k = p / NN_;
            int n = p - k*NN_;
            float4 v = *(const float4*)&band[(((size_t)b*NN_ + n)*NK + k)*NF + fq*4];
            *(float4*)&nf[(size_t)q*4] = v;
        }
    }
}

// ============ K2: topk + mask + MLP + sym + deg/clus, one block per (b,k) ============
// 1024 threads (16 waves = 4 waves/SIMD) for latency hiding — r12 at 512 thr was
// latency-exposed (Occ 22%, VALUBusy 36%). LDS identical 129.2 KB -> 1 block/CU.
// GEMM phases split 928 threads = 58 row-pairs x 16; acc[2][4]/acc[2][8] (fewer VGPR).
__global__ __launch_bounds__(1024, 1) void k_topk_mlpsym(const float* __restrict__ corr,
    const float* __restrict__ thadj,
    const float* __restrict__ W1, const float* __restrict__ b1,
    const float* __restrict__ W2, const float* __restrict__ b2,
    float* __restrict__ ia, float* __restrict__ deg_out, float* __restrict__ clus_out)
{
    __shared__ float smem[32308];
    float* sA  = smem;             // corr[121] -> sc[116] -> intra[121]
    float* sB  = smem + 14036;     // W1 then W2
    float* sH  = smem + 23764;     // [116][68]; sTop overlay first
    float* sb1 = smem + 31652;
    float* sb2 = smem + 31716;
    unsigned* sKm  = (unsigned*)(smem + 31844);
    unsigned* sTop = (unsigned*)sH;
    int bk = blockIdx.x, t = threadIdx.x;

    // P1: corr -> sA stride 121 (scalar stores); W1 -> sB; biases
    const float* src = corr + (size_t)bk*NN2;
    for (int e4 = t; e4 < NN2/4; e4 += 1024){
        int e = e4*4;
        int i = e / 116, j = e - i*116;
        float4 v = *(const float4*)&src[e];
        sA[i*121 + j + 0] = v.x;
        sA[i*121 + j + 1] = v.y;
        sA[i*121 + j + 2] = v.z;
        sA[i*121 + j + 3] = v.w;
    }
    for (int e4 = t; e4 < 1856; e4 += 1024)
        *(float4*)&sB[e4*4] = *(const float4*)&W1[e4*4];
    if (t < 64) sb1[t] = b1[t];
    if (t >= 64 && t < 192) sb2[t-64] = (t-64 < NN_) ? b2[t-64] : 0.0f;
    __syncthreads();

    // P2: top-10 per row, 4 threads/row, packed keys
    if (t < 464){
        int r = t >> 2, q = t & 3;
        const float* row = &sA[r*121 + q*29];
        int jbase = q*29;
        unsigned tv[TOPK];
        #pragma unroll
        for (int p = 0; p < TOPK; ++p) tv[p] = 0u;
        for (int jj = 0; jj < 29; ++jj){
            float c = fabsf(row[jj]);
            unsigned u = (__float_as_uint(c) & 0xFFFFFF80u) | (unsigned)(127 - (jbase + jj));
            #pragma unroll
            for (int p = 0; p < TOPK; ++p){
                unsigned old = tv[p];
                bool gt = u > old;
                tv[p] = gt ? u : old;
                u = gt ? old : u;
            }
        }
        #pragma unroll
        for (int p = 0; p < TOPK; ++p) sTop[t*10 + p] = tv[p];
    }
    __syncthreads();

    // P3: 4-way merge -> bitmask
    if (t < NN_){
        const unsigned* L0 = &sTop[(4*t+0)*10];
        const unsigned* L1 = &sTop[(4*t+1)*10];
        const unsigned* L2 = &sTop[(4*t+2)*10];
        const unsigned* L3 = &sTop[(4*t+3)*10];
        int i0=0, i1=0, i2=0, i3=0;
        unsigned m0=0,m1=0,m2=0,m3=0;
        #pragma unroll
        for (int p = 0; p < TOPK; ++p){
            unsigned u0 = L0[i0], u1 = L1[i1], u2 = L2[i2], u3 = L3[i3];
            unsigned ua = u0 > u1 ? u0 : u1;
            unsigned ub = u2 > u3 ? u2 : u3;
            unsigned u  = ua > ub ? ua : ub;
            if (u == u0) ++i0; else if (u == u1) ++i1; else if (u == u2) ++i2; else ++i3;
            int j = 127 - (int)(u & 127u);
            unsigned bit = 1u << (j & 31);
            int w = j >> 5;
            if (w == 0) m0 |= bit; else if (w == 1) m1 |= bit; else if (w == 2) m2 |= bit; else m3 |= bit;
        }
        sKm[t*4+0]=m0; sKm[t*4+1]=m1; sKm[t*4+2]=m2; sKm[t*4+3]=m3;
    }
    __syncthreads();

    // P4: sc = relu(sym(corr*tmask*kmask)); register-buffer then rewrite at stride 116
    {
        float th = 0.1f + sigmoidf_(thadj[0]) * 0.2f;
        float vb[14];
        #pragma unroll
        for (int it = 0; it < 14; ++it){
            int e = t + it*1024;
            float v = 0.0f;
            if (e < NN2){
                int i = e / 116, j = e - i*116;
                float cij = sA[i*121 + j];
                float cji = sA[j*121 + i];
                bool kij = (sKm[i*4 + (j>>5)] >> (j&31)) & 1u;
                bool kji = (sKm[j*4 + (i>>5)] >> (i&31)) & 1u;
                float mij = (fabsf(cij) > th && kij) ? cij : 0.0f;
                float mji = (fabsf(cji) > th && kji) ? cji : 0.0f;
                v = fmaxf(0.5f*(mij+mji), 0.0f);
            }
            vb[it] = v;
        }
        __syncthreads();
        #pragma unroll
        for (int it = 0; it < 14; ++it){
            int e = t + it*1024;
            if (e < NN2) sA[e] = vb[it];
        }
    }
    __syncthreads();

    // P5: mlp1: H[116][64] = relu(sc @ W1^T + b1); 928 thr = 58 row-pairs x 16 outs
    if (t < 928){
        int rg = t >> 4, og = t & 15;       // rg 0..57, rows rg and rg+58
        float acc[2][4] = {};
        for (int j4 = 0; j4 < 29; ++j4){
            float4 s[2], w[4];
            #pragma unroll
            for (int m = 0; m < 2; ++m) s[m] = *(const float4*)&sA[(rg+58*m)*116 + j4*4];
            #pragma unroll
            for (int n = 0; n < 4; ++n) w[n] = *(const float4*)&sB[(og+16*n)*116 + j4*4];
            #pragma unroll
            for (int m = 0; m < 2; ++m)
                #pragma unroll
                for (int n = 0; n < 4; ++n)
                    acc[m][n] += dot4_(s[m], w[n]);
        }
        #pragma unroll
        for (int m = 0; m < 2; ++m)
            #pragma unroll
            for (int n = 0; n < 4; ++n)
                sH[(rg+58*m)*68 + og+16*n] = fmaxf(acc[m][n] + sb1[og+16*n], 0.0f);
    }
    __syncthreads();

    // P6: W2 -> sB [128][76] (zero-padded rows >= 116)
    for (int e = t; e < 128*64; e += 1024){
        int j = e >> 6, o = e & 63;
        sB[j*76 + o] = (j < NN_) ? W2[e] : 0.0f;
    }
    __syncthreads();

    // P7: intra = sigmoid(H @ W2^T + b2) -> sA at stride 121; 928 thr
    if (t < 928){
        int rg = t >> 4, jg = t & 15;
        float acc[2][8] = {};
        for (int o4 = 0; o4 < 16; ++o4){
            float4 h[2], w[8];
            #pragma unroll
            for (int m = 0; m < 2; ++m) h[m] = *(const float4*)&sH[(rg+58*m)*68 + o4*4];
            #pragma unroll
            for (int q = 0; q < 8; ++q) w[q] = *(const float4*)&sB[(jg+16*q)*76 + o4*4];
            #pragma unroll
            for (int m = 0; m < 2; ++m)
                #pragma unroll
                for (int q = 0; q < 8; ++q)
                    acc[m][q] += dot4_(h[m], w[q]);
        }
        #pragma unroll
        for (int m = 0; m < 2; ++m){
            int row = rg + 58*m;
            #pragma unroll
            for (int q = 0; q < 8; ++q){
                int j = jg + 16*q;
                if (j < NN_)
                    sA[row*121 + j] = sigmoidf_(acc[m][q] + sb2[j]);
            }
        }
    }
    __syncthreads();

    // P8: sym -> ia ; deg/clus (stride 121 transpose)
    float* dia = ia + (size_t)bk*NN2;
    for (int e4 = t; e4 < NN2/4; e4 += 1024){
        int e = e4*4;
        int i = e / 116, j0 = e - i*116;
        float4 v;
        v.x = 0.5f*(sA[i*121+j0+0] + sA[(j0+0)*121+i]);
        v.y = 0.5f*(sA[i*121+j0+1] + sA[(j0+1)*121+i]);
        v.z = 0.5f*(sA[i*121+j0+2] + sA[(j0+2)*121+i]);
        v.w = 0.5f*(sA[i*121+j0+3] + sA[(j0+3)*121+i]);
        *(float4*)&dia[e] = v;
    }
    if (t < 464){
        int r = t >> 2, q = t & 3;
        float tri = 0.f, dg = 0.f;
        for (int jj = 0; jj < 29; ++jj){
            int j = q*29 + jj;
            float v = 0.5f*(sA[r*121+j] + sA[j*121+r]);
            tri = fmaf(v, v, tri);
            dg += (v > 0.f) ? 1.f : 0.f;
        }
        tri += __shfl_xor(tri,1); tri += __shfl_xor(tri,2);
        dg  += __shfl_xor(dg,1);  dg  += __shfl_xor(dg,2);
        if (q == 0){
            deg_out[(size_t)bk*NN_ + r]  = dg;
            clus_out[(size_t)bk*NN_ + r] = tri / (dg*dg + 1e-8f);
        }
    }
}

// ---------------- graph stats (incl. band mean/std) + graph linear (r7) ----------------
__global__ __launch_bounds__(256) void k_gstats_lin(const float* __restrict__ band,
    const float* __restrict__ deg, const float* __restrict__ clus,
    const float* __restrict__ dens, const float* __restrict__ stren,
    const float* __restrict__ Wc, const float* __restrict__ bc,
    float* __restrict__ gfo, float* __restrict__ aux)
{
    int b = blockIdx.x, t = threadIdx.x;
    __shared__ float sGf[152];
    __shared__ float sPs[18*14*4];
    __shared__ float sPq[18*14*4];
    __shared__ float sA[4], sB[4];

    if (t < 252){
        int fq = t % 18, g = t / 18;
        float4 s = make_float4(0,0,0,0), q = make_float4(0,0,0,0);
        const float* base = band + (size_t)b*(KN*NF);
        for (int nk = g; nk < KN; nk += 14){
            float4 v = *(const float4*)&base[nk*NF + fq*4];
            s.x += v.x; s.y += v.y; s.z += v.z; s.w += v.w;
            q.x = fmaf(v.x,v.x,q.x); q.y = fmaf(v.y,v.y,q.y);
            q.z = fmaf(v.z,v.z,q.z); q.w = fmaf(v.w,v.w,q.w);
        }
        int idx = (fq*14 + g)*4;
        *(float4*)&sPs[idx] = s;
        *(float4*)&sPq[idx] = q;
    }
    __syncthreads();
    if (t < NF){
        int fq = t >> 2, e = t & 3;
        float S = 0.f, Q = 0.f;
        for (int g = 0; g < 14; ++g){ S += sPs[(fq*14+g)*4+e]; Q += sPq[(fq*14+g)*4+e]; }
        float mean = S * (1.0f/(float)KN);
        float var = fmaxf((Q - S*mean)/((float)KN - 1.0f), 0.0f);
        sGf[t] = mean;
        sGf[NF + t] = sqrtf(var);
    }
    __syncthreads();

    float s = 0.f, ss = 0.f;
    for (int e = t; e < KN; e += 256){ float v = deg[(size_t)b*KN + e]; s += v; ss += v*v; }
    #pragma unroll
    for (int d = 1; d < 64; d <<= 1){ s += __shfl_xor(s,d); ss += __shfl_xor(ss,d); }
    if ((t & 63) == 0){ sA[t>>6] = s; sB[t>>6] = ss; }
    __syncthreads();
    if (t == 0){
        float S0 = sA[0]+sA[1]+sA[2]+sA[3], S1 = sB[0]+sB[1]+sB[2]+sB[3];
        float Mv = (float)KN, mean = S0/Mv;
        float var = fmaxf((S1 - S0*mean)/(Mv - 1.0f), 0.0f);
        sGf[144] = mean; sGf[145] = sqrtf(var);
        aux[b] = S0;
    }
    __syncthreads();

    s = 0.f; ss = 0.f;
    for (int e = t; e < KN; e += 256){ float v = clus[(size_t)b*KN + e]; s += v; ss += v*v; }
    #pragma unroll
    for (int d = 1; d < 64; d <<= 1){ s += __shfl_xor(s,d); ss += __shfl_xor(ss,d); }
    if ((t & 63) == 0){ sA[t>>6] = s; sB[t>>6] = ss; }
    __syncthreads();
    if (t == 0){
        float S0 = sA[0]+sA[1]+sA[2]+sA[3], S1 = sB[0]+sB[1]+sB[2]+sB[3];
        float Mv = (float)KN, mean = S0/Mv;
        float var = fmaxf((S1 - S0*mean)/(Mv - 1.0f), 0.0f);
        sGf[146] = mean; sGf[147] = sqrtf(var);
    }
    __syncthreads();

    s = 0.f; ss = 0.f;
    for (int e = t; e < NN_; e += 256){ s += dens[(size_t)b*NN_ + e]; ss += stren[(size_t)b*NN_ + e]; }
    #pragma unroll
    for (int d = 1; d < 64; d <<= 1){ s += __shfl_xor(s,d); ss += __shfl_xor(ss,d); }
    if ((t & 63) == 0){ sA[t>>6] = s; sB[t>>6] = ss; }
    __syncthreads();
    if (t == 0){
        float S0 = sA[0]+sA[1]+sA[2]+sA[3], S1 = sB[0]+sB[1]+sB[2]+sB[3];
        sGf[148] = S0 / (float)NN_;
        sGf[149] = S1 / (float)NN_;
        aux[128 + b] = S0 * 16.0f;
    }
    __syncthreads();

    if (t < 128){
        float acc = bc[t];
        const float* w = Wc + (size_t)t*150;
        for (int c = 0; c < 150; ++c) acc = fmaf(sGf[c], w[c], acc);
        gfo[(size_t)b*128 + t] = fmaxf(acc, 0.f);
    }
}

// ---------------- sparsity (fallback standalone) ----------------
__global__ __launch_bounds__(64) void k_sparsity(const float* __restrict__ aux, float* __restrict__ out3)
{
    int t = threadIdx.x;
    float a = aux[t] + aux[64 + t];
    float c = aux[128 + t] + aux[192 + t];
    #pragma unroll
    for (int d = 1; d < 64; d <<= 1){ a += __shfl_xor(a,d); c += __shfl_xor(c,d); }
    if (t == 0){
        const float it = 6889472.0f, jt = 237568.0f;
        float isp = 1.0f - a/it;
        float jsp = 1.0f - c/jt;
        out3[0] = isp; out3[1] = jsp;
        out3[2] = (isp*it + jsp*jt)/(it + jt);
    }
}

// ============ K4: unified assembly (grid-stride) + optional sparsity ============
__global__ __launch_bounds__(256) void k_uninf(const float* __restrict__ intra_adj,
    const float* __restrict__ inter_adj, const float* __restrict__ aux,
    float* __restrict__ uni, float* __restrict__ sp, int do_sp)
{
    if (do_sp && blockIdx.x == 0 && threadIdx.x < 64){
        int t = threadIdx.x;
        float a = aux[t] + aux[64 + t];
        float c = aux[128 + t] + aux[192 + t];
        #pragma unroll
        for (int d = 1; d < 64; d <<= 1){ a += __shfl_xor(a,d); c += __shfl_xor(c,d); }
        if (t == 0){
            const float it = 6889472.0f, jt = 237568.0f;
            float isp = 1.0f - a/it;
            float jsp = 1.0f - c/jt;
            sp[0] = isp; sp[1] = jsp;
            sp[2] = (isp*it + jsp*jt)/(it + jt);
        }
    }
    int gid = blockIdx.x*256 + threadIdx.x;
    int gsz = gridDim.x*256;
    for (int q = gid; q < UNQ; q += gsz){
        int row = q / 116;
        int cq  = q - row*116;
        int b = row / KN;
        int p = row - b*KN;
        int k1 = p / NN_;
        int i  = p - k1*NN_;
        int k2 = cq / 29;
        int j0 = cq*4 - k2*NN_;
        float4 v;
        if (k2 == k1){
            v = *(const float4*)&intra_adj[(((size_t)b*NK + k1)*NN_ + i)*NN_ + j0];
        } else {
            int d = i - j0;
            float val = 0.f;
            if (d >= 0 && d < 4)
                val = inter_adj[(((size_t)b*NN_ + i)*NK + k1)*NK + k2];
            v.x = (d==0)?val:0.f;
            v.y = (d==1)?val:0.f;
            v.z = (d==2)?val:0.f;
            v.w = (d==3)?val:0.f;
        }
        *(float4*)&uni[(size_t)q*4] = v;
    }
}

extern "C" void kernel_launch(void* const* d_in, const int* in_sizes, int n_in,
                              void* d_out, int out_size, void* d_ws, size_t ws_size,
                              hipStream_t stream)
{
    const float* band = (const float*)d_in[0];
    const float* attn = (const float*)d_in[1];
    const float* thA  = (const float*)d_in[2];
    const float* thE  = (const float*)d_in[3];
    const float* fw   = (const float*)d_in[4];
    const float* iW1  = (const float*)d_in[5];
    const float* ib1  = (const float*)d_in[6];
    const float* iW2  = (const float*)d_in[7];
    const float* ib2  = (const float*)d_in[8];
    const float* eW1  = (const float*)d_in[9];
    const float* eb1  = (const float*)d_in[10];
    const float* eW2  = (const float*)d_in[11];
    const float* eb2  = (const float*)d_in[12];
    const float* cW   = (const float*)d_in[13];
    const float* cb   = (const float*)d_in[14];

    float* out = (float*)d_out;
    float* uni = out + OFF_UNI;
    float* nf  = out + OFF_NF;
    float* gfo = out + OFF_GF;
    float* ia  = out + OFF_IA;
    float* ie  = out + OFF_IE;
    float* sp  = out + OFF_SP;

    float* scr_corr  = uni + SCR_CORR;
    float* scr_deg   = uni + SCR_DEG;
    float* scr_clus  = uni + SCR_CLUS;
    float* scr_dens  = uni + SCR_DENS;
    float* scr_stren = uni + SCR_STREN;

    int ws_ok = (ws_size >= 256*sizeof(float));
    float* aux = ws_ok ? (float*)d_ws : (uni + SCR_AUX);

    k_corr_inter<<<NB_CORR + NB_INTER + NB_COPY, 256, 0, stream>>>(
        band, attn, thE, fw, eW1, eb1, eW2, eb2,
        scr_corr, ie, scr_dens, scr_stren, nf);
    k_topk_mlpsym<<<BK, 1024, 0, stream>>>(scr_corr, thA, iW1, ib1, iW2, ib2,
                                           ia, scr_deg, scr_clus);
    k_gstats_lin<<<NB, 256, 0, stream>>>(band, scr_deg, scr_clus, scr_dens, scr_stren,
                                         cW, cb, gfo, aux);
    if (!ws_ok)
        k_sparsity<<<1, 64, 0, stream>>>(aux, sp);
    k_uninf<<<2048, 256, 0, stream>>>(ia, ie, aux, uni, sp, ws_ok ? 1 : 0);
}